// Round 7
// baseline (139.209 us; speedup 1.0000x reference)
//
#include <hip/hip_runtime.h>
#include <hip/hip_bf16.h>

typedef __attribute__((ext_vector_type(8))) short short8;
typedef __attribute__((ext_vector_type(4))) float f32x4;

__device__ __forceinline__ unsigned short f2bf(float f){
    union { float f; unsigned u; } uf; uf.f = f;
    unsigned u = uf.u;
    u += 0x7FFFu + ((u >> 16) & 1u);   // RNE
    return (unsigned short)(u >> 16);
}
__device__ __forceinline__ int pack2(float a, float b){
    return (int)((unsigned)f2bf(a) | ((unsigned)f2bf(b) << 16));
}
__device__ __forceinline__ unsigned cvtpk(float lo, float hi){
    unsigned r;
    asm("v_cvt_pk_bf16_f32 %0, %1, %2" : "=v"(r) : "v"(lo), "v"(hi));
    return r;
}
__device__ __forceinline__ f32x4 vmax4(f32x4 a, f32x4 b){
    f32x4 r; r[0]=fmaxf(a[0],b[0]); r[1]=fmaxf(a[1],b[1]);
    r[2]=fmaxf(a[2],b[2]); r[3]=fmaxf(a[3],b[3]); return r;
}

#define N_SPATIAL 1600
#define ATTN_SCALE 0.17677669529663687f  /* 32^-0.5 */

// ---------------- K1: x f32 (B,C,N) -> x_t bf16 (B,N,C) ----------------
__global__ __launch_bounds__(256) void k_xt(const float* __restrict__ x,
                                            unsigned short* __restrict__ x_t){
    int bi = blockIdx.x;              // B*50
    int b = bi / 50, nc = bi % 50;
    int n0 = nc * 32;
    int c = threadIdx.x;              // 0..255
    unsigned short vals[32];
    const float* src = x + ((size_t)(b*256 + c))*N_SPATIAL + n0;
    #pragma unroll
    for (int j=0;j<8;j++){
        float4 f = *reinterpret_cast<const float4*>(src + j*4);
        vals[j*4+0] = f2bf(f.x); vals[j*4+1] = f2bf(f.y);
        vals[j*4+2] = f2bf(f.z); vals[j*4+3] = f2bf(f.w);
    }
    unsigned short* dst = x_t + ((size_t)b*N_SPATIAL + n0)*256 + c;
    #pragma unroll
    for (int j=0;j<32;j++) dst[(size_t)j*256] = vals[j];
}

// ---------------- K2: v = x + BN(dwconv3x3(x)) , bf16 (B,C,N) ----------------
__global__ __launch_bounds__(256) void k_pev(const float* __restrict__ x,
                                             const float* __restrict__ pw,
                                             const float* __restrict__ pg,
                                             const float* __restrict__ pb,
                                             const float* __restrict__ pm,
                                             const float* __restrict__ pv,
                                             unsigned short* __restrict__ v){
    int idx = blockIdx.x*256 + threadIdx.x;      // < 4*256*1600
    int n  = idx % N_SPATIAL;
    int bc = idx / N_SPATIAL;
    int c  = bc & 255;
    int h = n / 40, w = n % 40;
    const float* xp = x + (size_t)bc*N_SPATIAL;
    float acc = 0.f;
    #pragma unroll
    for (int kh=-1; kh<=1; kh++){
        int hh = h + kh; if ((unsigned)hh >= 40u) continue;
        #pragma unroll
        for (int kw=-1; kw<=1; kw++){
            int ww = w + kw; if ((unsigned)ww >= 40u) continue;
            acc += xp[hh*40+ww] * pw[c*9 + (kh+1)*3 + (kw+1)];
        }
    }
    float inv = pg[c] * rsqrtf(pv[c] + 1e-5f);
    float out = xp[n] + acc*inv + (pb[c] - pm[c]*inv);
    v[idx] = f2bf(out);
}

// ---------------- K3: qkv = SiLU(BN(W @ X)) -> qk_t[b][grp][n][d], grp=o>>5 ----------------
__global__ __launch_bounds__(256) void k_qkv(const unsigned short* __restrict__ x_t,
                                             const float* __restrict__ wq,
                                             const float* __restrict__ g,
                                             const float* __restrict__ be,
                                             const float* __restrict__ mu,
                                             const float* __restrict__ va,
                                             unsigned short* __restrict__ qk_t){
    __shared__ alignas(16) unsigned short a_lds[64*32];
    __shared__ alignas(16) unsigned short b_lds[64*32];
    int bi = blockIdx.x;                      // 4*8*25
    int b = bi / 200, ot = (bi/25) % 8, nt = bi % 25;
    int o0 = ot*64, n0 = nt*64;
    int tid = threadIdx.x, w = tid>>6, lane = tid&63;
    int row = tid>>2, col8 = (tid&3)*8;
    f32x4 acc[4];
    #pragma unroll
    for (int t=0;t<4;t++) acc[t] = (f32x4){0.f,0.f,0.f,0.f};
    const float* asrc = wq + (size_t)(o0+row)*256 + col8;
    const unsigned short* bsrc = x_t + ((size_t)b*N_SPATIAL + n0 + row)*256 + col8;
    for (int k0=0; k0<256; k0+=32){
        float4 f0 = *reinterpret_cast<const float4*>(asrc + k0);
        float4 f1 = *reinterpret_cast<const float4*>(asrc + k0 + 4);
        int4 av; av.x = pack2(f0.x,f0.y); av.y = pack2(f0.z,f0.w);
                 av.z = pack2(f1.x,f1.y); av.w = pack2(f1.z,f1.w);
        *reinterpret_cast<int4*>(&a_lds[row*32 + col8]) = av;
        *reinterpret_cast<int4*>(&b_lds[row*32 + col8]) = *reinterpret_cast<const int4*>(bsrc + k0);
        __syncthreads();
        short8 af = *reinterpret_cast<const short8*>(&a_lds[(16*w + (lane&15))*32 + (lane>>4)*8]);
        #pragma unroll
        for (int t=0;t<4;t++){
            short8 bf = *reinterpret_cast<const short8*>(&b_lds[(16*t + (lane&15))*32 + (lane>>4)*8]);
            acc[t] = __builtin_amdgcn_mfma_f32_16x16x32_bf16(af, bf, acc[t], 0, 0, 0);
        }
        __syncthreads();
    }
    #pragma unroll
    for (int r=0;r<4;r++){
        int o = o0 + 16*w + (lane>>4)*4 + r;
        float inv = g[o] * rsqrtf(va[o] + 1e-5f);
        float b2  = be[o] - mu[o]*inv;
        int grp = o >> 5, d = o & 31;
        unsigned short* dst = qk_t + ((size_t)(b*16 + grp)*N_SPATIAL)*32 + d;
        #pragma unroll
        for (int t=0;t<4;t++){
            int n = n0 + 16*t + (lane&15);
            float z = acc[t][r]*inv + b2;
            float y = z / (1.f + __expf(-z));
            dst[(size_t)n*32] = f2bf(y);
        }
    }
}

// ---------------- K4 v3: flash attention, 4-wave in-block K-split, no split-K ws ----------------
// grid = 3200 (4b x 8h x 100 qt of 16 rows); wave w handles kt = w, w+4, ...
__global__ __launch_bounds__(256) void k_attn3(const unsigned short* __restrict__ qk_t,
                                               const unsigned short* __restrict__ v,
                                               unsigned short* __restrict__ ao_t){
    __shared__ float cmb_o[4][16][32];
    __shared__ float cmb_m[4][16];
    __shared__ float cmb_s[4][16];
    int bi = blockIdx.x;
    int b = bi/800, rem = bi%800, h = rem/100, qt = rem%100;
    int nq0 = qt*16;
    int tid = threadIdx.x, w = tid>>6, lane = tid&63;
    int ql = lane&15, lg = lane>>4;

    const unsigned short* qsrc = qk_t + ((size_t)(b*16+h)*N_SPATIAL)*32;
    const unsigned short* ksrc = qk_t + ((size_t)(b*16+8+h)*N_SPATIAL)*32;
    const unsigned short* vsrc = v + ((size_t)(b*256+h*32))*N_SPATIAL;

    short8 qf = *reinterpret_cast<const short8*>(qsrc + (size_t)(nq0 + ql)*32 + lg*8);

    const unsigned short* vrow0 = vsrc + (size_t)ql*N_SPATIAL;        // d = ql
    const unsigned short* vrow1 = vsrc + (size_t)(16+ql)*N_SPATIAL;   // d = 16+ql

    float M = -1e30f, S = 0.f;
    f32x4 o0 = (f32x4){0.f,0.f,0.f,0.f};
    f32x4 o1 = (f32x4){0.f,0.f,0.f,0.f};

    // prologue K prefetch for kt = w
    const unsigned short* kpc = ksrc + (size_t)(w*64 + ql)*32 + lg*8;
    short8 ka0 = *reinterpret_cast<const short8*>(kpc);
    short8 ka1 = *reinterpret_cast<const short8*>(kpc + 16*32);
    short8 ka2 = *reinterpret_cast<const short8*>(kpc + 32*32);
    short8 ka3 = *reinterpret_cast<const short8*>(kpc + 48*32);

    for (int kt = w; kt < 25; kt += 4){
        int kbase = kt*64;
        bool more = (kt+4 < 25);
        short8 kb0, kb1, kb2, kb3;
        if (more){
            const unsigned short* kpn = ksrc + (size_t)((kt+4)*64 + ql)*32 + lg*8;
            kb0 = *reinterpret_cast<const short8*>(kpn);
            kb1 = *reinterpret_cast<const short8*>(kpn + 16*32);
            kb2 = *reinterpret_cast<const short8*>(kpn + 32*32);
            kb3 = *reinterpret_cast<const short8*>(kpn + 48*32);
        }

        f32x4 z = (f32x4){0.f,0.f,0.f,0.f};
        f32x4 p0 = __builtin_amdgcn_mfma_f32_16x16x32_bf16(ka0, qf, z, 0,0,0);
        f32x4 p1 = __builtin_amdgcn_mfma_f32_16x16x32_bf16(ka1, qf, z, 0,0,0);
        f32x4 p2 = __builtin_amdgcn_mfma_f32_16x16x32_bf16(ka2, qf, z, 0,0,0);
        f32x4 p3 = __builtin_amdgcn_mfma_f32_16x16x32_bf16(ka3, qf, z, 0,0,0);

        // V loads for current tile (latency hidden under softmax VALU work)
        const unsigned short* v0p = vrow0 + kbase;
        const unsigned short* v1p = vrow1 + kbase;
        uint2 va0 = *reinterpret_cast<const uint2*>(v0p + 4*lg);
        uint2 va1 = *reinterpret_cast<const uint2*>(v0p + 16 + 4*lg);
        uint2 vb0 = *reinterpret_cast<const uint2*>(v0p + 32 + 4*lg);
        uint2 vb1 = *reinterpret_cast<const uint2*>(v0p + 48 + 4*lg);
        uint2 vc0 = *reinterpret_cast<const uint2*>(v1p + 4*lg);
        uint2 vc1 = *reinterpret_cast<const uint2*>(v1p + 16 + 4*lg);
        uint2 vd0 = *reinterpret_cast<const uint2*>(v1p + 32 + 4*lg);
        uint2 vd1 = *reinterpret_cast<const uint2*>(v1p + 48 + 4*lg);

        f32x4 mm = vmax4(vmax4(p0,p1), vmax4(p2,p3));
        float mx = fmaxf(fmaxf(mm[0],mm[1]), fmaxf(mm[2],mm[3]));
        mx = fmaxf(mx, __shfl_xor(mx, 16));
        mx = fmaxf(mx, __shfl_xor(mx, 32));
        float mn = fmaxf(M, mx);
        float al = __expf(ATTN_SCALE*(M - mn));
        float nb = -ATTN_SCALE*mn;
        #pragma unroll
        for (int r=0;r<4;r++){
            p0[r] = __expf(fmaf(p0[r], ATTN_SCALE, nb));
            p1[r] = __expf(fmaf(p1[r], ATTN_SCALE, nb));
            p2[r] = __expf(fmaf(p2[r], ATTN_SCALE, nb));
            p3[r] = __expf(fmaf(p3[r], ATTN_SCALE, nb));
        }
        float ts = ((p0[0]+p0[1])+(p0[2]+p0[3])) + ((p1[0]+p1[1])+(p1[2]+p1[3]))
                 + ((p2[0]+p2[1])+(p2[2]+p2[3])) + ((p3[0]+p3[1])+(p3[2]+p3[3]));
        ts += __shfl_xor(ts, 16);
        ts += __shfl_xor(ts, 32);
        S = S*al + ts;
        M = mn;
        o0 *= al; o1 *= al;

        union { int4 i; short8 s8; } pb0, pb1;
        pb0.i = make_int4((int)cvtpk(p0[0],p0[1]), (int)cvtpk(p0[2],p0[3]),
                          (int)cvtpk(p1[0],p1[1]), (int)cvtpk(p1[2],p1[3]));
        pb1.i = make_int4((int)cvtpk(p2[0],p2[1]), (int)cvtpk(p2[2],p2[3]),
                          (int)cvtpk(p3[0],p3[1]), (int)cvtpk(p3[2],p3[3]));

        union { int4 i; short8 s8; } vf;
        vf.i = make_int4((int)va0.x,(int)va0.y,(int)va1.x,(int)va1.y);
        o0 = __builtin_amdgcn_mfma_f32_16x16x32_bf16(vf.s8, pb0.s8, o0, 0,0,0);
        vf.i = make_int4((int)vb0.x,(int)vb0.y,(int)vb1.x,(int)vb1.y);
        o0 = __builtin_amdgcn_mfma_f32_16x16x32_bf16(vf.s8, pb1.s8, o0, 0,0,0);
        vf.i = make_int4((int)vc0.x,(int)vc0.y,(int)vc1.x,(int)vc1.y);
        o1 = __builtin_amdgcn_mfma_f32_16x16x32_bf16(vf.s8, pb0.s8, o1, 0,0,0);
        vf.i = make_int4((int)vd0.x,(int)vd0.y,(int)vd1.x,(int)vd1.y);
        o1 = __builtin_amdgcn_mfma_f32_16x16x32_bf16(vf.s8, pb1.s8, o1, 0,0,0);

        ka0 = kb0; ka1 = kb1; ka2 = kb2; ka3 = kb3;
    }

    // write per-wave partials
    #pragma unroll
    for (int r=0;r<4;r++){
        cmb_o[w][ql][4*lg + r]      = o0[r];
        cmb_o[w][ql][16 + 4*lg + r] = o1[r];
    }
    if (lg == 0){ cmb_m[w][ql] = M; cmb_s[w][ql] = S; }
    __syncthreads();

    // combine: thread t -> q = t>>4, d pair = (t&15)*2
    int q = tid>>4, dd = (tid&15)*2;
    float m0 = cmb_m[0][q], m1 = cmb_m[1][q], m2 = cmb_m[2][q], m3 = cmb_m[3][q];
    float mg = fmaxf(fmaxf(m0,m1), fmaxf(m2,m3));
    float e0 = __expf(ATTN_SCALE*(m0-mg)), e1 = __expf(ATTN_SCALE*(m1-mg));
    float e2 = __expf(ATTN_SCALE*(m2-mg)), e3 = __expf(ATTN_SCALE*(m3-mg));
    float den = e0*cmb_s[0][q] + e1*cmb_s[1][q] + e2*cmb_s[2][q] + e3*cmb_s[3][q];
    float a0 = e0*cmb_o[0][q][dd]   + e1*cmb_o[1][q][dd]   + e2*cmb_o[2][q][dd]   + e3*cmb_o[3][q][dd];
    float a1 = e0*cmb_o[0][q][dd+1] + e1*cmb_o[1][q][dd+1] + e2*cmb_o[2][q][dd+1] + e3*cmb_o[3][q][dd+1];
    float inv = 1.f/den;
    *reinterpret_cast<unsigned*>(ao_t + ((size_t)b*N_SPATIAL + nq0 + q)*256 + h*32 + dd) =
        (unsigned)pack2(a0*inv, a1*inv);
}

// ---------------- K5: out = SiLU(BN(proj_w @ AO)) -> FLOAT32 out ----------------
__global__ __launch_bounds__(256) void k_proj(const unsigned short* __restrict__ ao_t,
                                              const float* __restrict__ wp,
                                              const float* __restrict__ g,
                                              const float* __restrict__ be,
                                              const float* __restrict__ mu,
                                              const float* __restrict__ va,
                                              float* __restrict__ out){
    __shared__ alignas(16) unsigned short a_lds[64*32];
    __shared__ alignas(16) unsigned short b_lds[64*32];
    int bi = blockIdx.x;                      // 4*4*25
    int b = bi / 100, ot = (bi/25) % 4, nt = bi % 25;
    int o0 = ot*64, n0 = nt*64;
    int tid = threadIdx.x, w = tid>>6, lane = tid&63;
    int row = tid>>2, col8 = (tid&3)*8;
    f32x4 acc[4];
    #pragma unroll
    for (int t=0;t<4;t++) acc[t] = (f32x4){0.f,0.f,0.f,0.f};
    const float* asrc = wp + (size_t)(o0+row)*256 + col8;
    const unsigned short* bsrc = ao_t + ((size_t)b*N_SPATIAL + n0 + row)*256 + col8;
    for (int k0=0; k0<256; k0+=32){
        float4 f0 = *reinterpret_cast<const float4*>(asrc + k0);
        float4 f1 = *reinterpret_cast<const float4*>(asrc + k0 + 4);
        int4 av; av.x = pack2(f0.x,f0.y); av.y = pack2(f0.z,f0.w);
                 av.z = pack2(f1.x,f1.y); av.w = pack2(f1.z,f1.w);
        *reinterpret_cast<int4*>(&a_lds[row*32 + col8]) = av;
        *reinterpret_cast<int4*>(&b_lds[row*32 + col8]) = *reinterpret_cast<const int4*>(bsrc + k0);
        __syncthreads();
        short8 af = *reinterpret_cast<const short8*>(&a_lds[(16*w + (lane&15))*32 + (lane>>4)*8]);
        #pragma unroll
        for (int t=0;t<4;t++){
            short8 bf = *reinterpret_cast<const short8*>(&b_lds[(16*t + (lane&15))*32 + (lane>>4)*8]);
            acc[t] = __builtin_amdgcn_mfma_f32_16x16x32_bf16(af, bf, acc[t], 0, 0, 0);
        }
        __syncthreads();
    }
    #pragma unroll
    for (int r=0;r<4;r++){
        int o = o0 + 16*w + (lane>>4)*4 + r;
        float inv = g[o] * rsqrtf(va[o] + 1e-5f);
        float b2  = be[o] - mu[o]*inv;
        float* dst = out + ((size_t)(b*256 + o))*N_SPATIAL;
        #pragma unroll
        for (int t=0;t<4;t++){
            int n = n0 + 16*t + (lane&15);
            float z = acc[t][r]*inv + b2;
            float y = z / (1.f + __expf(-z));
            dst[n] = y;
        }
    }
}

extern "C" void kernel_launch(void* const* d_in, const int* in_sizes, int n_in,
                              void* d_out, int out_size, void* d_ws, size_t ws_size,
                              hipStream_t stream) {
    const float* x      = (const float*)d_in[0];
    const float* qkv_w  = (const float*)d_in[1];
    const float* qkv_g  = (const float*)d_in[2];
    const float* qkv_b  = (const float*)d_in[3];
    const float* qkv_m  = (const float*)d_in[4];
    const float* qkv_v  = (const float*)d_in[5];
    const float* proj_w = (const float*)d_in[6];
    const float* proj_g = (const float*)d_in[7];
    const float* proj_b = (const float*)d_in[8];
    const float* proj_m = (const float*)d_in[9];
    const float* proj_v = (const float*)d_in[10];
    const float* pe_w   = (const float*)d_in[11];
    const float* pe_g   = (const float*)d_in[12];
    const float* pe_b   = (const float*)d_in[13];
    const float* pe_m   = (const float*)d_in[14];
    const float* pe_v   = (const float*)d_in[15];

    char* ws = (char*)d_ws;
    unsigned short* x_t  = (unsigned short*)(ws);                 // 3,276,800
    unsigned short* vbuf = (unsigned short*)(ws + 3276800);       // 3,276,800
    unsigned short* qk_t = (unsigned short*)(ws + 6553600);       // 6,553,600
    unsigned short* ao_t = (unsigned short*)(ws + 13107200);      // 3,276,800
    float* outp = (float*)d_out;

    k_xt   <<<200, 256, 0, stream>>>(x, x_t);
    k_pev  <<<6400,256, 0, stream>>>(x, pe_w, pe_g, pe_b, pe_m, pe_v, vbuf);
    k_qkv  <<<800, 256, 0, stream>>>(x_t, qkv_w, qkv_g, qkv_b, qkv_m, qkv_v, qk_t);
    k_attn3<<<3200,256, 0, stream>>>(qk_t, vbuf, ao_t);
    k_proj <<<400, 256, 0, stream>>>(ao_t, proj_w, proj_g, proj_b, proj_m, proj_v, outp);
}

// Round 9
// 99.623 us; speedup vs baseline: 1.3974x; 1.3974x over previous
//
#include <hip/hip_runtime.h>
#include <hip/hip_bf16.h>

typedef __attribute__((ext_vector_type(8))) short short8;
typedef __attribute__((ext_vector_type(4))) float f32x4;

__device__ __forceinline__ unsigned short f2bf(float f){
    union { float f; unsigned u; } uf; uf.f = f;
    unsigned u = uf.u;
    u += 0x7FFFu + ((u >> 16) & 1u);   // RNE
    return (unsigned short)(u >> 16);
}
__device__ __forceinline__ int pack2(float a, float b){
    union { float f; unsigned u; } ua, ub; ua.f = a; ub.f = b;
    unsigned x = ua.u; x += 0x7FFFu + ((x >> 16) & 1u);
    unsigned y = ub.u; y += 0x7FFFu + ((y >> 16) & 1u);
    return (int)((x >> 16) | (y & 0xFFFF0000u));
}
__device__ __forceinline__ unsigned cvtpk(float lo, float hi){
    unsigned r;
    asm("v_cvt_pk_bf16_f32 %0, %1, %2" : "=v"(r) : "v"(lo), "v"(hi));
    return r;
}
__device__ __forceinline__ float fexp2(float x){
    return __builtin_amdgcn_exp2f(x);   // v_exp_f32: 2^x
}

#define N_SPATIAL 1600
// ATTN_SCALE * log2(e) folded into q at k_qkv: 0.17677669529663687 * 1.4426950408889634
#define QSCALE_LOG2E 0.25506601f

// ---------------- K1: x f32 (B,C,N) -> x_t bf16 (B,N,C) ----------------
__global__ __launch_bounds__(256) void k_xt(const float* __restrict__ x,
                                            unsigned short* __restrict__ x_t){
    int bi = blockIdx.x;              // B*50
    int b = bi / 50, nc = bi % 50;
    int n0 = nc * 32;
    int c = threadIdx.x;              // 0..255
    unsigned short vals[32];
    const float* src = x + ((size_t)(b*256 + c))*N_SPATIAL + n0;
    #pragma unroll
    for (int j=0;j<8;j++){
        float4 f = *reinterpret_cast<const float4*>(src + j*4);
        vals[j*4+0] = f2bf(f.x); vals[j*4+1] = f2bf(f.y);
        vals[j*4+2] = f2bf(f.z); vals[j*4+3] = f2bf(f.w);
    }
    unsigned short* dst = x_t + ((size_t)b*N_SPATIAL + n0)*256 + c;
    #pragma unroll
    for (int j=0;j<32;j++) dst[(size_t)j*256] = vals[j];
}

// ---------------- K2 v2: v = x + BN(dwconv3x3(x)) -> V in MFMA-fragment order ----------------
// v_mf[b][h][kt][frag][lane][j] ; frag = (d>=16)*2 + (key>=32);
// element (lane=(ql,lg), j) = V[d=(f>>1)*16+ql][key=(f&1)*32+(j>>2)*16+4*lg+(j&3)]
__global__ __launch_bounds__(256) void k_pev2(const float* __restrict__ x,
                                              const float* __restrict__ pw,
                                              const float* __restrict__ pg,
                                              const float* __restrict__ pb,
                                              const float* __restrict__ pm,
                                              const float* __restrict__ pv,
                                              unsigned short* __restrict__ v_mf){
    int bi = blockIdx.x;            // 800 = b*200 + h*25 + kt
    int b = bi/200, h=(bi/25)%8, kt=bi%25;
    int t = threadIdx.x;
    int f = t>>6, lane = t&63, ql = lane&15, lg = lane>>4;
    int d = (f>>1)*16 + ql;
    int c = h*32 + d;
    const float* xp = x + ((size_t)(b*256+c))*N_SPATIAL;
    float inv = pg[c]*rsqrtf(pv[c]+1e-5f);
    float bias = pb[c]-pm[c]*inv;
    const float* w9 = pw + c*9;
    float w00=w9[0],w01=w9[1],w02=w9[2],w10=w9[3],w11=w9[4],w12=w9[5],w20=w9[6],w21=w9[7],w22=w9[8];
    union { unsigned short u[8]; int4 i4; } vals;
    #pragma unroll
    for (int j=0;j<8;j++){
        int key = (f&1)*32 + (j>>2)*16 + 4*lg + (j&3);
        int n = kt*64 + key;
        int hh = n/40, ww = n%40;
        float acc = 0.f;
        if (hh > 0){
            if (ww > 0)  acc += xp[n-41]*w00;
                         acc += xp[n-40]*w01;
            if (ww < 39) acc += xp[n-39]*w02;
        }
        if (ww > 0)  acc += xp[n-1]*w10;
                     acc += xp[n]*w11;
        if (ww < 39) acc += xp[n+1]*w12;
        if (hh < 39){
            if (ww > 0)  acc += xp[n+39]*w20;
                         acc += xp[n+40]*w21;
            if (ww < 39) acc += xp[n+41]*w22;
        }
        float out = xp[n] + acc*inv + bias;
        vals.u[j] = f2bf(out);
    }
    *reinterpret_cast<int4*>(v_mf + ((size_t)(bi*4 + f)*64 + lane)*8) = vals.i4;
}

// ---------------- K3: qkv = SiLU(BN(W @ X)) -> qk_t[b][grp][n][d]; q channels pre-scaled ----------------
__global__ __launch_bounds__(256) void k_qkv(const unsigned short* __restrict__ x_t,
                                             const float* __restrict__ wq,
                                             const float* __restrict__ g,
                                             const float* __restrict__ be,
                                             const float* __restrict__ mu,
                                             const float* __restrict__ va,
                                             unsigned short* __restrict__ qk_t){
    __shared__ alignas(16) unsigned short a_lds[64*32];
    __shared__ alignas(16) unsigned short b_lds[64*32];
    int bi = blockIdx.x;                      // 4*8*25
    int b = bi / 200, ot = (bi/25) % 8, nt = bi % 25;
    int o0 = ot*64, n0 = nt*64;
    int tid = threadIdx.x, w = tid>>6, lane = tid&63;
    int row = tid>>2, col8 = (tid&3)*8;
    f32x4 acc[4];
    #pragma unroll
    for (int t=0;t<4;t++) acc[t] = (f32x4){0.f,0.f,0.f,0.f};
    const float* asrc = wq + (size_t)(o0+row)*256 + col8;
    const unsigned short* bsrc = x_t + ((size_t)b*N_SPATIAL + n0 + row)*256 + col8;
    for (int k0=0; k0<256; k0+=32){
        float4 f0 = *reinterpret_cast<const float4*>(asrc + k0);
        float4 f1 = *reinterpret_cast<const float4*>(asrc + k0 + 4);
        int4 av; av.x = pack2(f0.x,f0.y); av.y = pack2(f0.z,f0.w);
                 av.z = pack2(f1.x,f1.y); av.w = pack2(f1.z,f1.w);
        *reinterpret_cast<int4*>(&a_lds[row*32 + col8]) = av;
        *reinterpret_cast<int4*>(&b_lds[row*32 + col8]) = *reinterpret_cast<const int4*>(bsrc + k0);
        __syncthreads();
        short8 af = *reinterpret_cast<const short8*>(&a_lds[(16*w + (lane&15))*32 + (lane>>4)*8]);
        #pragma unroll
        for (int t=0;t<4;t++){
            short8 bf = *reinterpret_cast<const short8*>(&b_lds[(16*t + (lane&15))*32 + (lane>>4)*8]);
            acc[t] = __builtin_amdgcn_mfma_f32_16x16x32_bf16(af, bf, acc[t], 0, 0, 0);
        }
        __syncthreads();
    }
    #pragma unroll
    for (int r=0;r<4;r++){
        int o = o0 + 16*w + (lane>>4)*4 + r;
        float inv = g[o] * rsqrtf(va[o] + 1e-5f);
        float b2  = be[o] - mu[o]*inv;
        float qs  = (o < 256) ? QSCALE_LOG2E : 1.0f;
        int grp = o >> 5, d = o & 31;
        unsigned short* dst = qk_t + ((size_t)(b*16 + grp)*N_SPATIAL)*32 + d;
        #pragma unroll
        for (int t=0;t<4;t++){
            int n = n0 + 16*t + (lane&15);
            float z = acc[t][r]*inv + b2;
            float y = z / (1.f + __expf(-z));
            dst[(size_t)n*32] = f2bf(y * qs);
        }
    }
}

// ---------------- K4 v4: flash attention, shift-free exp2 softmax, frag-ordered V ----------------
// grid 800 (b,h,qt64); 4 independent waves (16q each, all 25 kt). Zero LDS, zero barriers.
__global__ __launch_bounds__(256) void k_attn4(const unsigned short* __restrict__ qk_t,
                                               const unsigned short* __restrict__ v_mf,
                                               unsigned short* __restrict__ ao_t){
    int bi = blockIdx.x;            // 800 = b*200 + h*25 + qt
    int b = bi/200, h = (bi/25)%8, qt = bi%25;
    int tid = threadIdx.x, w = tid>>6, lane = tid&63;
    int ql = lane&15, lg = lane>>4;
    int nq = qt*64 + w*16 + ql;

    const unsigned short* qsrc = qk_t + ((size_t)(b*16+h)*N_SPATIAL)*32;
    const unsigned short* ksrc = qk_t + ((size_t)(b*16+8+h)*N_SPATIAL)*32;
    const unsigned short* vms  = v_mf + (size_t)(b*200 + h*25)*2048 + lane*8;

    short8 qf = *reinterpret_cast<const short8*>(qsrc + (size_t)nq*32 + lg*8);
    const unsigned short* kp = ksrc + (size_t)ql*32 + lg*8;

    f32x4 o0 = (f32x4){0.f,0.f,0.f,0.f};
    f32x4 o1 = (f32x4){0.f,0.f,0.f,0.f};
    float Sp = 0.f;

    // preload kt = 0
    short8 ka0 = *reinterpret_cast<const short8*>(kp);
    short8 ka1 = *reinterpret_cast<const short8*>(kp + 512);
    short8 ka2 = *reinterpret_cast<const short8*>(kp + 1024);
    short8 ka3 = *reinterpret_cast<const short8*>(kp + 1536);
    short8 va0 = *reinterpret_cast<const short8*>(vms);
    short8 va1 = *reinterpret_cast<const short8*>(vms + 512);
    short8 va2 = *reinterpret_cast<const short8*>(vms + 1024);
    short8 va3 = *reinterpret_cast<const short8*>(vms + 1536);

    for (int kt = 0; kt < 25; ++kt){
        short8 kb0, kb1, kb2, kb3, vb0, vb1, vb2, vb3;
        if (kt < 24){
            const unsigned short* kn = kp + (kt+1)*2048;
            kb0 = *reinterpret_cast<const short8*>(kn);
            kb1 = *reinterpret_cast<const short8*>(kn + 512);
            kb2 = *reinterpret_cast<const short8*>(kn + 1024);
            kb3 = *reinterpret_cast<const short8*>(kn + 1536);
            const unsigned short* vn = vms + (kt+1)*2048;
            vb0 = *reinterpret_cast<const short8*>(vn);
            vb1 = *reinterpret_cast<const short8*>(vn + 512);
            vb2 = *reinterpret_cast<const short8*>(vn + 1024);
            vb3 = *reinterpret_cast<const short8*>(vn + 1536);
        }

        f32x4 z = (f32x4){0.f,0.f,0.f,0.f};
        f32x4 p0 = __builtin_amdgcn_mfma_f32_16x16x32_bf16(ka0, qf, z, 0,0,0);
        f32x4 p1 = __builtin_amdgcn_mfma_f32_16x16x32_bf16(ka1, qf, z, 0,0,0);
        f32x4 p2 = __builtin_amdgcn_mfma_f32_16x16x32_bf16(ka2, qf, z, 0,0,0);
        f32x4 p3 = __builtin_amdgcn_mfma_f32_16x16x32_bf16(ka3, qf, z, 0,0,0);

        // shift-free softmax numerator: p = 2^(score), scale folded into q upstream
        #pragma unroll
        for (int r=0;r<4;r++){
            p0[r] = fexp2(p0[r]);
            p1[r] = fexp2(p1[r]);
            p2[r] = fexp2(p2[r]);
            p3[r] = fexp2(p3[r]);
        }
        Sp += ((p0[0]+p0[1])+(p0[2]+p0[3])) + ((p1[0]+p1[1])+(p1[2]+p1[3]))
            + ((p2[0]+p2[1])+(p2[2]+p2[3])) + ((p3[0]+p3[1])+(p3[2]+p3[3]));

        union { int4 i; short8 s8; } pb0, pb1;
        pb0.i = make_int4((int)cvtpk(p0[0],p0[1]), (int)cvtpk(p0[2],p0[3]),
                          (int)cvtpk(p1[0],p1[1]), (int)cvtpk(p1[2],p1[3]));
        pb1.i = make_int4((int)cvtpk(p2[0],p2[1]), (int)cvtpk(p2[2],p2[3]),
                          (int)cvtpk(p3[0],p3[1]), (int)cvtpk(p3[2],p3[3]));

        o0 = __builtin_amdgcn_mfma_f32_16x16x32_bf16(va0, pb0.s8, o0, 0,0,0);
        o0 = __builtin_amdgcn_mfma_f32_16x16x32_bf16(va1, pb1.s8, o0, 0,0,0);
        o1 = __builtin_amdgcn_mfma_f32_16x16x32_bf16(va2, pb0.s8, o1, 0,0,0);
        o1 = __builtin_amdgcn_mfma_f32_16x16x32_bf16(va3, pb1.s8, o1, 0,0,0);

        ka0 = kb0; ka1 = kb1; ka2 = kb2; ka3 = kb3;
        va0 = vb0; va1 = vb1; va2 = vb2; va3 = vb3;
    }

    // one-time S reduction across the 4 lg lanes sharing q
    Sp += __shfl_xor(Sp, 16);
    Sp += __shfl_xor(Sp, 32);
    float inv = 1.f / Sp;

    size_t rowoff = ((size_t)b*N_SPATIAL + nq)*256 + h*32;
    uint2 w0 = make_uint2((unsigned)pack2(o0[0]*inv, o0[1]*inv),
                          (unsigned)pack2(o0[2]*inv, o0[3]*inv));
    *reinterpret_cast<uint2*>(ao_t + rowoff + 4*lg) = w0;
    uint2 w1 = make_uint2((unsigned)pack2(o1[0]*inv, o1[1]*inv),
                          (unsigned)pack2(o1[2]*inv, o1[3]*inv));
    *reinterpret_cast<uint2*>(ao_t + rowoff + 16 + 4*lg) = w1;
}

// ---------------- K5: out = SiLU(BN(proj_w @ AO)) -> FLOAT32 out ----------------
__global__ __launch_bounds__(256) void k_proj(const unsigned short* __restrict__ ao_t,
                                              const float* __restrict__ wp,
                                              const float* __restrict__ g,
                                              const float* __restrict__ be,
                                              const float* __restrict__ mu,
                                              const float* __restrict__ va,
                                              float* __restrict__ out){
    __shared__ alignas(16) unsigned short a_lds[64*32];
    __shared__ alignas(16) unsigned short b_lds[64*32];
    int bi = blockIdx.x;                      // 4*4*25
    int b = bi / 100, ot = (bi/25) % 4, nt = bi % 25;
    int o0 = ot*64, n0 = nt*64;
    int tid = threadIdx.x, w = tid>>6, lane = tid&63;
    int row = tid>>2, col8 = (tid&3)*8;
    f32x4 acc[4];
    #pragma unroll
    for (int t=0;t<4;t++) acc[t] = (f32x4){0.f,0.f,0.f,0.f};
    const float* asrc = wp + (size_t)(o0+row)*256 + col8;
    const unsigned short* bsrc = ao_t + ((size_t)b*N_SPATIAL + n0 + row)*256 + col8;
    for (int k0=0; k0<256; k0+=32){
        float4 f0 = *reinterpret_cast<const float4*>(asrc + k0);
        float4 f1 = *reinterpret_cast<const float4*>(asrc + k0 + 4);
        int4 av; av.x = pack2(f0.x,f0.y); av.y = pack2(f0.z,f0.w);
                 av.z = pack2(f1.x,f1.y); av.w = pack2(f1.z,f1.w);
        *reinterpret_cast<int4*>(&a_lds[row*32 + col8]) = av;
        *reinterpret_cast<int4*>(&b_lds[row*32 + col8]) = *reinterpret_cast<const int4*>(bsrc + k0);
        __syncthreads();
        short8 af = *reinterpret_cast<const short8*>(&a_lds[(16*w + (lane&15))*32 + (lane>>4)*8]);
        #pragma unroll
        for (int t=0;t<4;t++){
            short8 bf = *reinterpret_cast<const short8*>(&b_lds[(16*t + (lane&15))*32 + (lane>>4)*8]);
            acc[t] = __builtin_amdgcn_mfma_f32_16x16x32_bf16(af, bf, acc[t], 0, 0, 0);
        }
        __syncthreads();
    }
    #pragma unroll
    for (int r=0;r<4;r++){
        int o = o0 + 16*w + (lane>>4)*4 + r;
        float inv = g[o] * rsqrtf(va[o] + 1e-5f);
        float b2  = be[o] - mu[o]*inv;
        float* dst = out + ((size_t)(b*256 + o))*N_SPATIAL;
        #pragma unroll
        for (int t=0;t<4;t++){
            int n = n0 + 16*t + (lane&15);
            float z = acc[t][r]*inv + b2;
            float y = z / (1.f + __expf(-z));
            dst[n] = y;
        }
    }
}

extern "C" void kernel_launch(void* const* d_in, const int* in_sizes, int n_in,
                              void* d_out, int out_size, void* d_ws, size_t ws_size,
                              hipStream_t stream) {
    const float* x      = (const float*)d_in[0];
    const float* qkv_w  = (const float*)d_in[1];
    const float* qkv_g  = (const float*)d_in[2];
    const float* qkv_b  = (const float*)d_in[3];
    const float* qkv_m  = (const float*)d_in[4];
    const float* qkv_v  = (const float*)d_in[5];
    const float* proj_w = (const float*)d_in[6];
    const float* proj_g = (const float*)d_in[7];
    const float* proj_b = (const float*)d_in[8];
    const float* proj_m = (const float*)d_in[9];
    const float* proj_v = (const float*)d_in[10];
    const float* pe_w   = (const float*)d_in[11];
    const float* pe_g   = (const float*)d_in[12];
    const float* pe_b   = (const float*)d_in[13];
    const float* pe_m   = (const float*)d_in[14];
    const float* pe_v   = (const float*)d_in[15];

    char* ws = (char*)d_ws;
    unsigned short* x_t  = (unsigned short*)(ws);                 // 3,276,800
    unsigned short* v_mf = (unsigned short*)(ws + 3276800);       // 3,276,800
    unsigned short* qk_t = (unsigned short*)(ws + 6553600);       // 6,553,600
    unsigned short* ao_t = (unsigned short*)(ws + 13107200);      // 3,276,800
    float* outp = (float*)d_out;

    k_xt   <<<200, 256, 0, stream>>>(x, x_t);
    k_pev2 <<<800, 256, 0, stream>>>(x, pe_w, pe_g, pe_b, pe_m, pe_v, v_mf);
    k_qkv  <<<800, 256, 0, stream>>>(x_t, qkv_w, qkv_g, qkv_b, qkv_m, qkv_v, qk_t);
    k_attn4<<<800, 256, 0, stream>>>(qk_t, v_mf, ao_t);
    k_proj <<<400, 256, 0, stream>>>(ao_t, proj_w, proj_g, proj_b, proj_m, proj_v, outp);
}

// Round 10
// 83.845 us; speedup vs baseline: 1.6603x; 1.1882x over previous
//
#include <hip/hip_runtime.h>
#include <hip/hip_bf16.h>

typedef __attribute__((ext_vector_type(8))) short short8;
typedef __attribute__((ext_vector_type(4))) float f32x4;

__device__ __forceinline__ unsigned short f2bf(float f){
    union { float f; unsigned u; } uf; uf.f = f;
    unsigned u = uf.u;
    u += 0x7FFFu + ((u >> 16) & 1u);   // RNE
    return (unsigned short)(u >> 16);
}
__device__ __forceinline__ int pack2(float a, float b){
    union { float f; unsigned u; } ua, ub; ua.f = a; ub.f = b;
    unsigned x = ua.u; x += 0x7FFFu + ((x >> 16) & 1u);
    unsigned y = ub.u; y += 0x7FFFu + ((y >> 16) & 1u);
    return (int)((x >> 16) | (y & 0xFFFF0000u));
}
__device__ __forceinline__ unsigned cvtpk(float lo, float hi){
    unsigned r;
    asm("v_cvt_pk_bf16_f32 %0, %1, %2" : "=v"(r) : "v"(lo), "v"(hi));
    return r;
}
__device__ __forceinline__ float fexp2(float x){
    return __builtin_amdgcn_exp2f(x);   // v_exp_f32: 2^x
}

#define N_SPATIAL 1600
// ATTN_SCALE * log2(e) folded into q at k_qkv
#define QSCALE_LOG2E 0.25506601f

// ---------------- K1: x f32 (B,C,N) -> x_t bf16 (B,N,C) ----------------
__global__ __launch_bounds__(256) void k_xt(const float* __restrict__ x,
                                            unsigned short* __restrict__ x_t){
    int bi = blockIdx.x;              // B*50
    int b = bi / 50, nc = bi % 50;
    int n0 = nc * 32;
    int c = threadIdx.x;              // 0..255
    unsigned short vals[32];
    const float* src = x + ((size_t)(b*256 + c))*N_SPATIAL + n0;
    #pragma unroll
    for (int j=0;j<8;j++){
        float4 f = *reinterpret_cast<const float4*>(src + j*4);
        vals[j*4+0] = f2bf(f.x); vals[j*4+1] = f2bf(f.y);
        vals[j*4+2] = f2bf(f.z); vals[j*4+3] = f2bf(f.w);
    }
    unsigned short* dst = x_t + ((size_t)b*N_SPATIAL + n0)*256 + c;
    #pragma unroll
    for (int j=0;j<32;j++) dst[(size_t)j*256] = vals[j];
}

// ---------------- K2 v3: v = x + BN(dwconv3x3(x)) -> V in MFMA-fragment order, LDS-staged ----------------
// v_mf[b][h][kt][frag][lane][j] ; frag f: d=(f>>1)*16+ql, key=(f&1)*32+(j>>2)*16+4*lg+(j&3)
__global__ __launch_bounds__(256) void k_pev3(const float* __restrict__ x,
                                              const float* __restrict__ pw,
                                              const float* __restrict__ pg,
                                              const float* __restrict__ pb,
                                              const float* __restrict__ pm,
                                              const float* __restrict__ pv,
                                              unsigned short* __restrict__ v_mf){
    __shared__ float xs[32][163];     // 160-col window + 3 pad (winStart = kt*64-48)
    int bi = blockIdx.x;              // 800 = b*200 + h*25 + kt
    int b = bi/200, h=(bi/25)%8, kt=bi%25;
    int t = threadIdx.x;
    int winStart = kt*64 - 48;
    const float* xbase = x + ((size_t)(b*256 + h*32))*N_SPATIAL;
    #pragma unroll
    for (int i=0;i<20;i++){
        int idx = t + i*256;          // < 5120 = 32*160
        int row = idx / 160, col = idx - row*160;
        int n = winStart + col;
        float val = ((unsigned)n < 1600u) ? xbase[(size_t)row*N_SPATIAL + n] : 0.f;
        xs[row][col] = val;
    }
    __syncthreads();

    int f = t>>6, lane = t&63, ql = lane&15, lg = lane>>4;
    int d = (f>>1)*16 + ql;
    int c = h*32 + d;
    float inv = pg[c]*rsqrtf(pv[c]+1e-5f);
    float bias = pb[c]-pm[c]*inv;
    const float* w9 = pw + c*9;
    float w00=w9[0],w01=w9[1],w02=w9[2],w10=w9[3],w11=w9[4],w12=w9[5],w20=w9[6],w21=w9[7],w22=w9[8];
    const float* xr = xs[d];
    union { unsigned short u[8]; int4 i4; } vals;
    #pragma unroll
    for (int j=0;j<8;j++){
        int key = (f&1)*32 + (j>>2)*16 + 4*lg + (j&3);
        int n = kt*64 + key;
        int hh = n/40, ww = n - hh*40;
        int col = key + 48;
        float acc = 0.f;
        if (hh > 0){
            if (ww > 0)  acc += xr[col-41]*w00;
                         acc += xr[col-40]*w01;
            if (ww < 39) acc += xr[col-39]*w02;
        }
        if (ww > 0)  acc += xr[col-1]*w10;
                     acc += xr[col]*w11;
        if (ww < 39) acc += xr[col+1]*w12;
        if (hh < 39){
            if (ww > 0)  acc += xr[col+39]*w20;
                         acc += xr[col+40]*w21;
            if (ww < 39) acc += xr[col+41]*w22;
        }
        float out = xr[col] + acc*inv + bias;
        vals.u[j] = f2bf(out);
    }
    *reinterpret_cast<int4*>(v_mf + ((size_t)(bi*4 + f)*64 + lane)*8) = vals.i4;
}

// ---------------- K3: qkv = SiLU(BN(W @ X)) -> qk_t[b][grp][n][d]; q channels pre-scaled ----------------
__global__ __launch_bounds__(256) void k_qkv(const unsigned short* __restrict__ x_t,
                                             const float* __restrict__ wq,
                                             const float* __restrict__ g,
                                             const float* __restrict__ be,
                                             const float* __restrict__ mu,
                                             const float* __restrict__ va,
                                             unsigned short* __restrict__ qk_t){
    __shared__ alignas(16) unsigned short a_lds[64*32];
    __shared__ alignas(16) unsigned short b_lds[64*32];
    int bi = blockIdx.x;                      // 4*8*25
    int b = bi / 200, ot = (bi/25) % 8, nt = bi % 25;
    int o0 = ot*64, n0 = nt*64;
    int tid = threadIdx.x, w = tid>>6, lane = tid&63;
    int row = tid>>2, col8 = (tid&3)*8;
    f32x4 acc[4];
    #pragma unroll
    for (int t=0;t<4;t++) acc[t] = (f32x4){0.f,0.f,0.f,0.f};
    const float* asrc = wq + (size_t)(o0+row)*256 + col8;
    const unsigned short* bsrc = x_t + ((size_t)b*N_SPATIAL + n0 + row)*256 + col8;
    for (int k0=0; k0<256; k0+=32){
        float4 f0 = *reinterpret_cast<const float4*>(asrc + k0);
        float4 f1 = *reinterpret_cast<const float4*>(asrc + k0 + 4);
        int4 av; av.x = pack2(f0.x,f0.y); av.y = pack2(f0.z,f0.w);
                 av.z = pack2(f1.x,f1.y); av.w = pack2(f1.z,f1.w);
        *reinterpret_cast<int4*>(&a_lds[row*32 + col8]) = av;
        *reinterpret_cast<int4*>(&b_lds[row*32 + col8]) = *reinterpret_cast<const int4*>(bsrc + k0);
        __syncthreads();
        short8 af = *reinterpret_cast<const short8*>(&a_lds[(16*w + (lane&15))*32 + (lane>>4)*8]);
        #pragma unroll
        for (int t=0;t<4;t++){
            short8 bf = *reinterpret_cast<const short8*>(&b_lds[(16*t + (lane&15))*32 + (lane>>4)*8]);
            acc[t] = __builtin_amdgcn_mfma_f32_16x16x32_bf16(af, bf, acc[t], 0, 0, 0);
        }
        __syncthreads();
    }
    #pragma unroll
    for (int r=0;r<4;r++){
        int o = o0 + 16*w + (lane>>4)*4 + r;
        float inv = g[o] * rsqrtf(va[o] + 1e-5f);
        float b2  = be[o] - mu[o]*inv;
        float qs  = (o < 256) ? QSCALE_LOG2E : 1.0f;
        int grp = o >> 5, d = o & 31;
        unsigned short* dst = qk_t + ((size_t)(b*16 + grp)*N_SPATIAL)*32 + d;
        #pragma unroll
        for (int t=0;t<4;t++){
            int n = n0 + 16*t + (lane&15);
            float z = acc[t][r]*inv + b2;
            float y = z / (1.f + __expf(-z));
            dst[(size_t)n*32] = f2bf(y * qs);
        }
    }
}

// ---------------- K4 v5: attention, 8 waves, in-block additive split-K (shift-free exp2) ----------------
// grid 800 (b,h,qt64); 8 waves: pair p=w>>1 owns 16 q-rows, half=w&1 covers kt {0..12}/{13..24}.
__global__ __launch_bounds__(512) void k_attn5(const unsigned short* __restrict__ qk_t,
                                               const unsigned short* __restrict__ v_mf,
                                               unsigned short* __restrict__ ao_t){
    __shared__ float cmb[8][16][33];
    __shared__ float cmbS[8][16];
    int bi = blockIdx.x;            // 800 = b*200 + h*25 + qt
    int b = bi/200, h = (bi/25)%8, qt = bi%25;
    int tid = threadIdx.x, w = tid>>6, lane = tid&63;
    int ql = lane&15, lg = lane>>4;
    int p = w>>1, half = w&1;
    int nq = qt*64 + p*16 + ql;

    const unsigned short* qsrc = qk_t + ((size_t)(b*16+h)*N_SPATIAL)*32;
    const unsigned short* ksrc = qk_t + ((size_t)(b*16+8+h)*N_SPATIAL)*32;
    const unsigned short* vms  = v_mf + (size_t)(b*200 + h*25)*2048 + lane*8;

    short8 qf = *reinterpret_cast<const short8*>(qsrc + (size_t)nq*32 + lg*8);

    int kt0 = half ? 13 : 0, kt1 = half ? 25 : 13;
    const unsigned short* kcur = ksrc + (size_t)(kt0*64 + ql)*32 + lg*8;
    const unsigned short* vcur = vms + (size_t)kt0*2048;

    f32x4 o0 = (f32x4){0.f,0.f,0.f,0.f};
    f32x4 o1 = (f32x4){0.f,0.f,0.f,0.f};
    float Sp = 0.f;

    short8 ka0 = *reinterpret_cast<const short8*>(kcur);
    short8 ka1 = *reinterpret_cast<const short8*>(kcur + 512);
    short8 ka2 = *reinterpret_cast<const short8*>(kcur + 1024);
    short8 ka3 = *reinterpret_cast<const short8*>(kcur + 1536);
    short8 va0 = *reinterpret_cast<const short8*>(vcur);
    short8 va1 = *reinterpret_cast<const short8*>(vcur + 512);
    short8 va2 = *reinterpret_cast<const short8*>(vcur + 1024);
    short8 va3 = *reinterpret_cast<const short8*>(vcur + 1536);

    for (int kt = kt0; kt < kt1; ++kt){
        short8 kb0, kb1, kb2, kb3, vb0, vb1, vb2, vb3;
        if (kt+1 < kt1){
            kcur += 2048; vcur += 2048;
            kb0 = *reinterpret_cast<const short8*>(kcur);
            kb1 = *reinterpret_cast<const short8*>(kcur + 512);
            kb2 = *reinterpret_cast<const short8*>(kcur + 1024);
            kb3 = *reinterpret_cast<const short8*>(kcur + 1536);
            vb0 = *reinterpret_cast<const short8*>(vcur);
            vb1 = *reinterpret_cast<const short8*>(vcur + 512);
            vb2 = *reinterpret_cast<const short8*>(vcur + 1024);
            vb3 = *reinterpret_cast<const short8*>(vcur + 1536);
        }

        f32x4 z = (f32x4){0.f,0.f,0.f,0.f};
        f32x4 p0 = __builtin_amdgcn_mfma_f32_16x16x32_bf16(ka0, qf, z, 0,0,0);
        f32x4 p1 = __builtin_amdgcn_mfma_f32_16x16x32_bf16(ka1, qf, z, 0,0,0);
        f32x4 p2 = __builtin_amdgcn_mfma_f32_16x16x32_bf16(ka2, qf, z, 0,0,0);
        f32x4 p3 = __builtin_amdgcn_mfma_f32_16x16x32_bf16(ka3, qf, z, 0,0,0);

        #pragma unroll
        for (int r=0;r<4;r++){
            p0[r] = fexp2(p0[r]);
            p1[r] = fexp2(p1[r]);
            p2[r] = fexp2(p2[r]);
            p3[r] = fexp2(p3[r]);
        }
        Sp += ((p0[0]+p0[1])+(p0[2]+p0[3])) + ((p1[0]+p1[1])+(p1[2]+p1[3]))
            + ((p2[0]+p2[1])+(p2[2]+p2[3])) + ((p3[0]+p3[1])+(p3[2]+p3[3]));

        union { int4 i; short8 s8; } pb0, pb1;
        pb0.i = make_int4((int)cvtpk(p0[0],p0[1]), (int)cvtpk(p0[2],p0[3]),
                          (int)cvtpk(p1[0],p1[1]), (int)cvtpk(p1[2],p1[3]));
        pb1.i = make_int4((int)cvtpk(p2[0],p2[1]), (int)cvtpk(p2[2],p2[3]),
                          (int)cvtpk(p3[0],p3[1]), (int)cvtpk(p3[2],p3[3]));

        o0 = __builtin_amdgcn_mfma_f32_16x16x32_bf16(va0, pb0.s8, o0, 0,0,0);
        o0 = __builtin_amdgcn_mfma_f32_16x16x32_bf16(va1, pb1.s8, o0, 0,0,0);
        o1 = __builtin_amdgcn_mfma_f32_16x16x32_bf16(va2, pb0.s8, o1, 0,0,0);
        o1 = __builtin_amdgcn_mfma_f32_16x16x32_bf16(va3, pb1.s8, o1, 0,0,0);

        ka0 = kb0; ka1 = kb1; ka2 = kb2; ka3 = kb3;
        va0 = vb0; va1 = vb1; va2 = vb2; va3 = vb3;
    }

    // per-wave S reduction across lg, then additive cross-half combine in LDS
    Sp += __shfl_xor(Sp, 16);
    Sp += __shfl_xor(Sp, 32);
    #pragma unroll
    for (int r=0;r<4;r++){
        cmb[w][ql][4*lg + r]      = o0[r];
        cmb[w][ql][16 + 4*lg + r] = o1[r];
    }
    if (lg == 0) cmbS[w][ql] = Sp;
    __syncthreads();

    if (half == 0){
        float St = cmbS[w][ql] + cmbS[w+1][ql];
        float inv = 1.f / St;
        f32x4 a0, a1;
        #pragma unroll
        for (int r=0;r<4;r++){
            a0[r] = (cmb[w][ql][4*lg + r]      + cmb[w+1][ql][4*lg + r]) * inv;
            a1[r] = (cmb[w][ql][16 + 4*lg + r] + cmb[w+1][ql][16 + 4*lg + r]) * inv;
        }
        size_t rowoff = ((size_t)b*N_SPATIAL + nq)*256 + h*32;
        uint2 w0 = make_uint2((unsigned)pack2(a0[0], a0[1]), (unsigned)pack2(a0[2], a0[3]));
        *reinterpret_cast<uint2*>(ao_t + rowoff + 4*lg) = w0;
        uint2 w1 = make_uint2((unsigned)pack2(a1[0], a1[1]), (unsigned)pack2(a1[2], a1[3]));
        *reinterpret_cast<uint2*>(ao_t + rowoff + 16 + 4*lg) = w1;
    }
}

// ---------------- K5: out = SiLU(BN(proj_w @ AO)) -> FLOAT32 out ----------------
__global__ __launch_bounds__(256) void k_proj(const unsigned short* __restrict__ ao_t,
                                              const float* __restrict__ wp,
                                              const float* __restrict__ g,
                                              const float* __restrict__ be,
                                              const float* __restrict__ mu,
                                              const float* __restrict__ va,
                                              float* __restrict__ out){
    __shared__ alignas(16) unsigned short a_lds[64*32];
    __shared__ alignas(16) unsigned short b_lds[64*32];
    int bi = blockIdx.x;                      // 4*4*25
    int b = bi / 100, ot = (bi/25) % 4, nt = bi % 25;
    int o0 = ot*64, n0 = nt*64;
    int tid = threadIdx.x, w = tid>>6, lane = tid&63;
    int row = tid>>2, col8 = (tid&3)*8;
    f32x4 acc[4];
    #pragma unroll
    for (int t=0;t<4;t++) acc[t] = (f32x4){0.f,0.f,0.f,0.f};
    const float* asrc = wp + (size_t)(o0+row)*256 + col8;
    const unsigned short* bsrc = ao_t + ((size_t)b*N_SPATIAL + n0 + row)*256 + col8;
    for (int k0=0; k0<256; k0+=32){
        float4 f0 = *reinterpret_cast<const float4*>(asrc + k0);
        float4 f1 = *reinterpret_cast<const float4*>(asrc + k0 + 4);
        int4 av; av.x = pack2(f0.x,f0.y); av.y = pack2(f0.z,f0.w);
                 av.z = pack2(f1.x,f1.y); av.w = pack2(f1.z,f1.w);
        *reinterpret_cast<int4*>(&a_lds[row*32 + col8]) = av;
        *reinterpret_cast<int4*>(&b_lds[row*32 + col8]) = *reinterpret_cast<const int4*>(bsrc + k0);
        __syncthreads();
        short8 af = *reinterpret_cast<const short8*>(&a_lds[(16*w + (lane&15))*32 + (lane>>4)*8]);
        #pragma unroll
        for (int t=0;t<4;t++){
            short8 bf = *reinterpret_cast<const short8*>(&b_lds[(16*t + (lane&15))*32 + (lane>>4)*8]);
            acc[t] = __builtin_amdgcn_mfma_f32_16x16x32_bf16(af, bf, acc[t], 0, 0, 0);
        }
        __syncthreads();
    }
    #pragma unroll
    for (int r=0;r<4;r++){
        int o = o0 + 16*w + (lane>>4)*4 + r;
        float inv = g[o] * rsqrtf(va[o] + 1e-5f);
        float b2  = be[o] - mu[o]*inv;
        float* dst = out + ((size_t)(b*256 + o))*N_SPATIAL;
        #pragma unroll
        for (int t=0;t<4;t++){
            int n = n0 + 16*t + (lane&15);
            float z = acc[t][r]*inv + b2;
            float y = z / (1.f + __expf(-z));
            dst[n] = y;
        }
    }
}

extern "C" void kernel_launch(void* const* d_in, const int* in_sizes, int n_in,
                              void* d_out, int out_size, void* d_ws, size_t ws_size,
                              hipStream_t stream) {
    const float* x      = (const float*)d_in[0];
    const float* qkv_w  = (const float*)d_in[1];
    const float* qkv_g  = (const float*)d_in[2];
    const float* qkv_b  = (const float*)d_in[3];
    const float* qkv_m  = (const float*)d_in[4];
    const float* qkv_v  = (const float*)d_in[5];
    const float* proj_w = (const float*)d_in[6];
    const float* proj_g = (const float*)d_in[7];
    const float* proj_b = (const float*)d_in[8];
    const float* proj_m = (const float*)d_in[9];
    const float* proj_v = (const float*)d_in[10];
    const float* pe_w   = (const float*)d_in[11];
    const float* pe_g   = (const float*)d_in[12];
    const float* pe_b   = (const float*)d_in[13];
    const float* pe_m   = (const float*)d_in[14];
    const float* pe_v   = (const float*)d_in[15];

    char* ws = (char*)d_ws;
    unsigned short* x_t  = (unsigned short*)(ws);                 // 3,276,800
    unsigned short* v_mf = (unsigned short*)(ws + 3276800);       // 3,276,800
    unsigned short* qk_t = (unsigned short*)(ws + 6553600);       // 6,553,600
    unsigned short* ao_t = (unsigned short*)(ws + 13107200);      // 3,276,800
    float* outp = (float*)d_out;

    k_xt   <<<200, 256, 0, stream>>>(x, x_t);
    k_pev3 <<<800, 256, 0, stream>>>(x, pe_w, pe_g, pe_b, pe_m, pe_v, v_mf);
    k_qkv  <<<800, 256, 0, stream>>>(x_t, qkv_w, qkv_g, qkv_b, qkv_m, qkv_v, qk_t);
    k_attn5<<<800, 512, 0, stream>>>(qk_t, v_mf, ao_t);
    k_proj <<<400, 256, 0, stream>>>(ao_t, proj_w, proj_g, proj_b, proj_m, proj_v, outp);
}

// Round 11
// 71.891 us; speedup vs baseline: 1.9364x; 1.1663x over previous
//
#include <hip/hip_runtime.h>
#include <hip/hip_bf16.h>

typedef __attribute__((ext_vector_type(8))) short short8;
typedef __attribute__((ext_vector_type(4))) float f32x4;

__device__ __forceinline__ unsigned short f2bf(float f){
    union { float f; unsigned u; } uf; uf.f = f;
    unsigned u = uf.u;
    u += 0x7FFFu + ((u >> 16) & 1u);   // RNE
    return (unsigned short)(u >> 16);
}
__device__ __forceinline__ int pack2(float a, float b){
    union { float f; unsigned u; } ua, ub; ua.f = a; ub.f = b;
    unsigned x = ua.u; x += 0x7FFFu + ((x >> 16) & 1u);
    unsigned y = ub.u; y += 0x7FFFu + ((y >> 16) & 1u);
    return (int)((x >> 16) | (y & 0xFFFF0000u));
}
__device__ __forceinline__ unsigned cvtpk(float lo, float hi){
    unsigned r;
    asm("v_cvt_pk_bf16_f32 %0, %1, %2" : "=v"(r) : "v"(lo), "v"(hi));
    return r;
}
__device__ __forceinline__ float fexp2(float x){
    return __builtin_amdgcn_exp2f(x);   // v_exp_f32: 2^x
}

#define N_SPATIAL 1600
// ATTN_SCALE * log2(e) folded into q at k_qkv
#define QSCALE_LOG2E 0.25506601f

// ---------------- K1: x f32 (B,C,N) -> x_t bf16 (B,N,C) ----------------
__global__ __launch_bounds__(256) void k_xt(const float* __restrict__ x,
                                            unsigned short* __restrict__ x_t){
    int bi = blockIdx.x;              // B*50
    int b = bi / 50, nc = bi % 50;
    int n0 = nc * 32;
    int c = threadIdx.x;              // 0..255
    unsigned short vals[32];
    const float* src = x + ((size_t)(b*256 + c))*N_SPATIAL + n0;
    #pragma unroll
    for (int j=0;j<8;j++){
        float4 f = *reinterpret_cast<const float4*>(src + j*4);
        vals[j*4+0] = f2bf(f.x); vals[j*4+1] = f2bf(f.y);
        vals[j*4+2] = f2bf(f.z); vals[j*4+3] = f2bf(f.w);
    }
    unsigned short* dst = x_t + ((size_t)b*N_SPATIAL + n0)*256 + c;
    #pragma unroll
    for (int j=0;j<32;j++) dst[(size_t)j*256] = vals[j];
}

// ---------------- K2 v3: v = x + BN(dwconv3x3(x)) -> V in MFMA-fragment order, LDS-staged ----------------
// v_mf[b][h][kt][frag][lane][j] ; frag f: d=(f>>1)*16+ql, key=(f&1)*32+(j>>2)*16+4*lg+(j&3)
__global__ __launch_bounds__(256) void k_pev3(const float* __restrict__ x,
                                              const float* __restrict__ pw,
                                              const float* __restrict__ pg,
                                              const float* __restrict__ pb,
                                              const float* __restrict__ pm,
                                              const float* __restrict__ pv,
                                              unsigned short* __restrict__ v_mf){
    __shared__ float xs[32][163];     // 160-col window + 3 pad (winStart = kt*64-48)
    int bi = blockIdx.x;              // 800 = b*200 + h*25 + kt
    int b = bi/200, h=(bi/25)%8, kt=bi%25;
    int t = threadIdx.x;
    int winStart = kt*64 - 48;
    const float* xbase = x + ((size_t)(b*256 + h*32))*N_SPATIAL;
    #pragma unroll
    for (int i=0;i<20;i++){
        int idx = t + i*256;          // < 5120 = 32*160
        int row = idx / 160, col = idx - row*160;
        int n = winStart + col;
        float val = ((unsigned)n < 1600u) ? xbase[(size_t)row*N_SPATIAL + n] : 0.f;
        xs[row][col] = val;
    }
    __syncthreads();

    int f = t>>6, lane = t&63, ql = lane&15, lg = lane>>4;
    int d = (f>>1)*16 + ql;
    int c = h*32 + d;
    float inv = pg[c]*rsqrtf(pv[c]+1e-5f);
    float bias = pb[c]-pm[c]*inv;
    const float* w9 = pw + c*9;
    float w00=w9[0],w01=w9[1],w02=w9[2],w10=w9[3],w11=w9[4],w12=w9[5],w20=w9[6],w21=w9[7],w22=w9[8];
    const float* xr = xs[d];
    union { unsigned short u[8]; int4 i4; } vals;
    #pragma unroll
    for (int j=0;j<8;j++){
        int key = (f&1)*32 + (j>>2)*16 + 4*lg + (j&3);
        int n = kt*64 + key;
        int hh = n/40, ww = n - hh*40;
        int col = key + 48;
        float acc = 0.f;
        if (hh > 0){
            if (ww > 0)  acc += xr[col-41]*w00;
                         acc += xr[col-40]*w01;
            if (ww < 39) acc += xr[col-39]*w02;
        }
        if (ww > 0)  acc += xr[col-1]*w10;
                     acc += xr[col]*w11;
        if (ww < 39) acc += xr[col+1]*w12;
        if (hh < 39){
            if (ww > 0)  acc += xr[col+39]*w20;
                         acc += xr[col+40]*w21;
            if (ww < 39) acc += xr[col+41]*w22;
        }
        float out = xr[col] + acc*inv + bias;
        vals.u[j] = f2bf(out);
    }
    *reinterpret_cast<int4*>(v_mf + ((size_t)(bi*4 + f)*64 + lane)*8) = vals.i4;
}

// ---------------- K3: qkv = SiLU(BN(W @ X)) -> qk_t[b][grp][n][d]; q channels pre-scaled ----------------
__global__ __launch_bounds__(256) void k_qkv(const unsigned short* __restrict__ x_t,
                                             const float* __restrict__ wq,
                                             const float* __restrict__ g,
                                             const float* __restrict__ be,
                                             const float* __restrict__ mu,
                                             const float* __restrict__ va,
                                             unsigned short* __restrict__ qk_t){
    __shared__ alignas(16) unsigned short a_lds[64*32];
    __shared__ alignas(16) unsigned short b_lds[64*32];
    int bi = blockIdx.x;                      // 4*8*25
    int b = bi / 200, ot = (bi/25) % 8, nt = bi % 25;
    int o0 = ot*64, n0 = nt*64;
    int tid = threadIdx.x, w = tid>>6, lane = tid&63;
    int row = tid>>2, col8 = (tid&3)*8;
    f32x4 acc[4];
    #pragma unroll
    for (int t=0;t<4;t++) acc[t] = (f32x4){0.f,0.f,0.f,0.f};
    const float* asrc = wq + (size_t)(o0+row)*256 + col8;
    const unsigned short* bsrc = x_t + ((size_t)b*N_SPATIAL + n0 + row)*256 + col8;
    for (int k0=0; k0<256; k0+=32){
        float4 f0 = *reinterpret_cast<const float4*>(asrc + k0);
        float4 f1 = *reinterpret_cast<const float4*>(asrc + k0 + 4);
        int4 av; av.x = pack2(f0.x,f0.y); av.y = pack2(f0.z,f0.w);
                 av.z = pack2(f1.x,f1.y); av.w = pack2(f1.z,f1.w);
        *reinterpret_cast<int4*>(&a_lds[row*32 + col8]) = av;
        *reinterpret_cast<int4*>(&b_lds[row*32 + col8]) = *reinterpret_cast<const int4*>(bsrc + k0);
        __syncthreads();
        short8 af = *reinterpret_cast<const short8*>(&a_lds[(16*w + (lane&15))*32 + (lane>>4)*8]);
        #pragma unroll
        for (int t=0;t<4;t++){
            short8 bf = *reinterpret_cast<const short8*>(&b_lds[(16*t + (lane&15))*32 + (lane>>4)*8]);
            acc[t] = __builtin_amdgcn_mfma_f32_16x16x32_bf16(af, bf, acc[t], 0, 0, 0);
        }
        __syncthreads();
    }
    #pragma unroll
    for (int r=0;r<4;r++){
        int o = o0 + 16*w + (lane>>4)*4 + r;
        float inv = g[o] * rsqrtf(va[o] + 1e-5f);
        float b2  = be[o] - mu[o]*inv;
        float qs  = (o < 256) ? QSCALE_LOG2E : 1.0f;
        int grp = o >> 5, d = o & 31;
        unsigned short* dst = qk_t + ((size_t)(b*16 + grp)*N_SPATIAL)*32 + d;
        #pragma unroll
        for (int t=0;t<4;t++){
            int n = n0 + 16*t + (lane&15);
            float z = acc[t][r]*inv + b2;
            float y = z / (1.f + __expf(-z));
            dst[(size_t)n*32] = f2bf(y * qs);
        }
    }
}

// ---------------- K4 v6: attention, LDS-staged K/V, pipelined, 4 waves x 16q x 25 tiles ----------------
// K LDS: padded stride 40 u16 (80B) -> conflict-free b128 reads; V LDS: linear (frag-ordered).
__global__ __launch_bounds__(256) void k_attn6(const unsigned short* __restrict__ qk_t,
                                               const unsigned short* __restrict__ v_mf,
                                               unsigned short* __restrict__ ao_t){
    __shared__ alignas(16) unsigned short k_lds[2][64*40];   // 10,240 B
    __shared__ alignas(16) unsigned short v_lds[2][2048];    //  8,192 B
    int bi = blockIdx.x;            // 800 = b*200 + h*25 + qt
    int b = bi/200, h = (bi/25)%8, qt = bi%25;
    int tid = threadIdx.x, w = tid>>6, lane = tid&63;
    int ql = lane&15, lg = lane>>4;
    int nq = qt*64 + w*16 + ql;

    const unsigned short* qsrc = qk_t + ((size_t)(b*16+h)*N_SPATIAL)*32;
    const unsigned short* ksrc = qk_t + ((size_t)(b*16+8+h)*N_SPATIAL)*32;  // [1600][32]
    const unsigned short* vms  = v_mf + (size_t)(b*200 + h*25)*2048;

    short8 qf = *reinterpret_cast<const short8*>(qsrc + (size_t)nq*32 + lg*8);

    // staging: thread covers one 16B chunk of each 4KB tile
    const unsigned short* kg = ksrc + tid*8;
    const unsigned short* vg = vms  + tid*8;
    unsigned short* kd = &k_lds[0][0] + (tid>>2)*40 + (tid&3)*8;
    unsigned short* vd = &v_lds[0][0] + tid*8;

    // prologue: tile0 -> LDS buf0 ; tile1 -> regs
    {
        int4 sk0 = *reinterpret_cast<const int4*>(kg);
        int4 sv0 = *reinterpret_cast<const int4*>(vg);
        *reinterpret_cast<int4*>(kd) = sk0;
        *reinterpret_cast<int4*>(vd) = sv0;
    }
    int4 skA = *reinterpret_cast<const int4*>(kg + 2048);
    int4 svA = *reinterpret_cast<const int4*>(vg + 2048);
    __syncthreads();

    f32x4 o0 = (f32x4){0.f,0.f,0.f,0.f};
    f32x4 o1 = (f32x4){0.f,0.f,0.f,0.f};
    float Sp = 0.f;

    for (int kt = 0; kt < 25; ++kt){
        int cur = kt & 1;
        // push tile kt+1 (in regs) into the idle buffer
        if (kt < 24){
            *reinterpret_cast<int4*>(kd + (cur^1)*2560) = skA;
            *reinterpret_cast<int4*>(vd + (cur^1)*2048) = svA;
        }
        // fetch tile kt+2 into regs (a full iteration of latency slack)
        int4 skB, svB;
        if (kt < 23){
            skB = *reinterpret_cast<const int4*>(kg + (size_t)(kt+2)*2048);
            svB = *reinterpret_cast<const int4*>(vg + (size_t)(kt+2)*2048);
        }

        const unsigned short* kb = &k_lds[cur][0];
        const unsigned short* vb = &v_lds[cur][0];
        short8 ka0 = *reinterpret_cast<const short8*>(kb + (size_t)( 0 + ql)*40 + lg*8);
        short8 ka1 = *reinterpret_cast<const short8*>(kb + (size_t)(16 + ql)*40 + lg*8);
        short8 ka2 = *reinterpret_cast<const short8*>(kb + (size_t)(32 + ql)*40 + lg*8);
        short8 ka3 = *reinterpret_cast<const short8*>(kb + (size_t)(48 + ql)*40 + lg*8);

        f32x4 z = (f32x4){0.f,0.f,0.f,0.f};
        f32x4 p0 = __builtin_amdgcn_mfma_f32_16x16x32_bf16(ka0, qf, z, 0,0,0);
        f32x4 p1 = __builtin_amdgcn_mfma_f32_16x16x32_bf16(ka1, qf, z, 0,0,0);
        f32x4 p2 = __builtin_amdgcn_mfma_f32_16x16x32_bf16(ka2, qf, z, 0,0,0);
        f32x4 p3 = __builtin_amdgcn_mfma_f32_16x16x32_bf16(ka3, qf, z, 0,0,0);

        #pragma unroll
        for (int r=0;r<4;r++){
            p0[r] = fexp2(p0[r]);
            p1[r] = fexp2(p1[r]);
            p2[r] = fexp2(p2[r]);
            p3[r] = fexp2(p3[r]);
        }
        Sp += ((p0[0]+p0[1])+(p0[2]+p0[3])) + ((p1[0]+p1[1])+(p1[2]+p1[3]))
            + ((p2[0]+p2[1])+(p2[2]+p2[3])) + ((p3[0]+p3[1])+(p3[2]+p3[3]));

        union { int4 i; short8 s8; } pb0, pb1;
        pb0.i = make_int4((int)cvtpk(p0[0],p0[1]), (int)cvtpk(p0[2],p0[3]),
                          (int)cvtpk(p1[0],p1[1]), (int)cvtpk(p1[2],p1[3]));
        pb1.i = make_int4((int)cvtpk(p2[0],p2[1]), (int)cvtpk(p2[2],p2[3]),
                          (int)cvtpk(p3[0],p3[1]), (int)cvtpk(p3[2],p3[3]));

        short8 va0 = *reinterpret_cast<const short8*>(vb +    0 + lane*8);
        short8 va1 = *reinterpret_cast<const short8*>(vb +  512 + lane*8);
        short8 va2 = *reinterpret_cast<const short8*>(vb + 1024 + lane*8);
        short8 va3 = *reinterpret_cast<const short8*>(vb + 1536 + lane*8);

        o0 = __builtin_amdgcn_mfma_f32_16x16x32_bf16(va0, pb0.s8, o0, 0,0,0);
        o0 = __builtin_amdgcn_mfma_f32_16x16x32_bf16(va1, pb1.s8, o0, 0,0,0);
        o1 = __builtin_amdgcn_mfma_f32_16x16x32_bf16(va2, pb0.s8, o1, 0,0,0);
        o1 = __builtin_amdgcn_mfma_f32_16x16x32_bf16(va3, pb1.s8, o1, 0,0,0);

        __syncthreads();
        skA = skB; svA = svB;
    }

    // one-time S reduction across the 4 lg lanes sharing q
    Sp += __shfl_xor(Sp, 16);
    Sp += __shfl_xor(Sp, 32);
    float inv = 1.f / Sp;

    size_t rowoff = ((size_t)b*N_SPATIAL + nq)*256 + h*32;
    uint2 w0 = make_uint2((unsigned)pack2(o0[0]*inv, o0[1]*inv),
                          (unsigned)pack2(o0[2]*inv, o0[3]*inv));
    *reinterpret_cast<uint2*>(ao_t + rowoff + 4*lg) = w0;
    uint2 w1 = make_uint2((unsigned)pack2(o1[0]*inv, o1[1]*inv),
                          (unsigned)pack2(o1[2]*inv, o1[3]*inv));
    *reinterpret_cast<uint2*>(ao_t + rowoff + 16 + 4*lg) = w1;
}

// ---------------- K5: out = SiLU(BN(proj_w @ AO)) -> FLOAT32 out ----------------
__global__ __launch_bounds__(256) void k_proj(const unsigned short* __restrict__ ao_t,
                                              const float* __restrict__ wp,
                                              const float* __restrict__ g,
                                              const float* __restrict__ be,
                                              const float* __restrict__ mu,
                                              const float* __restrict__ va,
                                              float* __restrict__ out){
    __shared__ alignas(16) unsigned short a_lds[64*32];
    __shared__ alignas(16) unsigned short b_lds[64*32];
    int bi = blockIdx.x;                      // 4*4*25
    int b = bi / 100, ot = (bi/25) % 4, nt = bi % 25;
    int o0 = ot*64, n0 = nt*64;
    int tid = threadIdx.x, w = tid>>6, lane = tid&63;
    int row = tid>>2, col8 = (tid&3)*8;
    f32x4 acc[4];
    #pragma unroll
    for (int t=0;t<4;t++) acc[t] = (f32x4){0.f,0.f,0.f,0.f};
    const float* asrc = wp + (size_t)(o0+row)*256 + col8;
    const unsigned short* bsrc = ao_t + ((size_t)b*N_SPATIAL + n0 + row)*256 + col8;
    for (int k0=0; k0<256; k0+=32){
        float4 f0 = *reinterpret_cast<const float4*>(asrc + k0);
        float4 f1 = *reinterpret_cast<const float4*>(asrc + k0 + 4);
        int4 av; av.x = pack2(f0.x,f0.y); av.y = pack2(f0.z,f0.w);
                 av.z = pack2(f1.x,f1.y); av.w = pack2(f1.z,f1.w);
        *reinterpret_cast<int4*>(&a_lds[row*32 + col8]) = av;
        *reinterpret_cast<int4*>(&b_lds[row*32 + col8]) = *reinterpret_cast<const int4*>(bsrc + k0);
        __syncthreads();
        short8 af = *reinterpret_cast<const short8*>(&a_lds[(16*w + (lane&15))*32 + (lane>>4)*8]);
        #pragma unroll
        for (int t=0;t<4;t++){
            short8 bf = *reinterpret_cast<const short8*>(&b_lds[(16*t + (lane&15))*32 + (lane>>4)*8]);
            acc[t] = __builtin_amdgcn_mfma_f32_16x16x32_bf16(af, bf, acc[t], 0, 0, 0);
        }
        __syncthreads();
    }
    #pragma unroll
    for (int r=0;r<4;r++){
        int o = o0 + 16*w + (lane>>4)*4 + r;
        float inv = g[o] * rsqrtf(va[o] + 1e-5f);
        float b2  = be[o] - mu[o]*inv;
        float* dst = out + ((size_t)(b*256 + o))*N_SPATIAL;
        #pragma unroll
        for (int t=0;t<4;t++){
            int n = n0 + 16*t + (lane&15);
            float z = acc[t][r]*inv + b2;
            float y = z / (1.f + __expf(-z));
            dst[n] = y;
        }
    }
}

extern "C" void kernel_launch(void* const* d_in, const int* in_sizes, int n_in,
                              void* d_out, int out_size, void* d_ws, size_t ws_size,
                              hipStream_t stream) {
    const float* x      = (const float*)d_in[0];
    const float* qkv_w  = (const float*)d_in[1];
    const float* qkv_g  = (const float*)d_in[2];
    const float* qkv_b  = (const float*)d_in[3];
    const float* qkv_m  = (const float*)d_in[4];
    const float* qkv_v  = (const float*)d_in[5];
    const float* proj_w = (const float*)d_in[6];
    const float* proj_g = (const float*)d_in[7];
    const float* proj_b = (const float*)d_in[8];
    const float* proj_m = (const float*)d_in[9];
    const float* proj_v = (const float*)d_in[10];
    const float* pe_w   = (const float*)d_in[11];
    const float* pe_g   = (const float*)d_in[12];
    const float* pe_b   = (const float*)d_in[13];
    const float* pe_m   = (const float*)d_in[14];
    const float* pe_v   = (const float*)d_in[15];

    char* ws = (char*)d_ws;
    unsigned short* x_t  = (unsigned short*)(ws);                 // 3,276,800
    unsigned short* v_mf = (unsigned short*)(ws + 3276800);       // 3,276,800
    unsigned short* qk_t = (unsigned short*)(ws + 6553600);       // 6,553,600
    unsigned short* ao_t = (unsigned short*)(ws + 13107200);      // 3,276,800
    float* outp = (float*)d_out;

    k_xt   <<<200, 256, 0, stream>>>(x, x_t);
    k_pev3 <<<800, 256, 0, stream>>>(x, pe_w, pe_g, pe_b, pe_m, pe_v, v_mf);
    k_qkv  <<<800, 256, 0, stream>>>(x_t, qkv_w, qkv_g, qkv_b, qkv_m, qkv_v, qk_t);
    k_attn6<<<800, 256, 0, stream>>>(qk_t, v_mf, ao_t);
    k_proj <<<400, 256, 0, stream>>>(ao_t, proj_w, proj_g, proj_b, proj_m, proj_v, outp);
}

// Round 12
// 68.830 us; speedup vs baseline: 2.0225x; 1.0445x over previous
//
#include <hip/hip_runtime.h>
#include <hip/hip_bf16.h>

typedef __attribute__((ext_vector_type(8))) short short8;
typedef __attribute__((ext_vector_type(4))) float f32x4;

__device__ __forceinline__ unsigned short f2bf(float f){
    union { float f; unsigned u; } uf; uf.f = f;
    unsigned u = uf.u;
    u += 0x7FFFu + ((u >> 16) & 1u);   // RNE
    return (unsigned short)(u >> 16);
}
__device__ __forceinline__ int pack2(float a, float b){
    union { float f; unsigned u; } ua, ub; ua.f = a; ub.f = b;
    unsigned x = ua.u; x += 0x7FFFu + ((x >> 16) & 1u);
    unsigned y = ub.u; y += 0x7FFFu + ((y >> 16) & 1u);
    return (int)((x >> 16) | (y & 0xFFFF0000u));
}
__device__ __forceinline__ unsigned cvtpk(float lo, float hi){
    unsigned r;
    asm("v_cvt_pk_bf16_f32 %0, %1, %2" : "=v"(r) : "v"(lo), "v"(hi));
    return r;
}
__device__ __forceinline__ float fexp2(float x){
    return __builtin_amdgcn_exp2f(x);   // v_exp_f32: 2^x
}

#define N_SPATIAL 1600
// ATTN_SCALE * log2(e) folded into q at k_qkv
#define QSCALE_LOG2E 0.25506601f

// ---------------- K1: x f32 (B,C,N) -> x_t bf16 (B,N,C) ----------------
__global__ __launch_bounds__(256) void k_xt(const float* __restrict__ x,
                                            unsigned short* __restrict__ x_t){
    int bi = blockIdx.x;              // B*50
    int b = bi / 50, nc = bi % 50;
    int n0 = nc * 32;
    int c = threadIdx.x;              // 0..255
    unsigned short vals[32];
    const float* src = x + ((size_t)(b*256 + c))*N_SPATIAL + n0;
    #pragma unroll
    for (int j=0;j<8;j++){
        float4 f = *reinterpret_cast<const float4*>(src + j*4);
        vals[j*4+0] = f2bf(f.x); vals[j*4+1] = f2bf(f.y);
        vals[j*4+2] = f2bf(f.z); vals[j*4+3] = f2bf(f.w);
    }
    unsigned short* dst = x_t + ((size_t)b*N_SPATIAL + n0)*256 + c;
    #pragma unroll
    for (int j=0;j<32;j++) dst[(size_t)j*256] = vals[j];
}

// ---------------- K2 v3: v = x + BN(dwconv3x3(x)) -> V in MFMA-fragment order, LDS-staged ----------------
__global__ __launch_bounds__(256) void k_pev3(const float* __restrict__ x,
                                              const float* __restrict__ pw,
                                              const float* __restrict__ pg,
                                              const float* __restrict__ pb,
                                              const float* __restrict__ pm,
                                              const float* __restrict__ pv,
                                              unsigned short* __restrict__ v_mf){
    __shared__ float xs[32][163];     // 160-col window + 3 pad (winStart = kt*64-48)
    int bi = blockIdx.x;              // 800 = b*200 + h*25 + kt
    int b = bi/200, h=(bi/25)%8, kt=bi%25;
    int t = threadIdx.x;
    int winStart = kt*64 - 48;
    const float* xbase = x + ((size_t)(b*256 + h*32))*N_SPATIAL;
    #pragma unroll
    for (int i=0;i<20;i++){
        int idx = t + i*256;          // < 5120 = 32*160
        int row = idx / 160, col = idx - row*160;
        int n = winStart + col;
        float val = ((unsigned)n < 1600u) ? xbase[(size_t)row*N_SPATIAL + n] : 0.f;
        xs[row][col] = val;
    }
    __syncthreads();

    int f = t>>6, lane = t&63, ql = lane&15, lg = lane>>4;
    int d = (f>>1)*16 + ql;
    int c = h*32 + d;
    float inv = pg[c]*rsqrtf(pv[c]+1e-5f);
    float bias = pb[c]-pm[c]*inv;
    const float* w9 = pw + c*9;
    float w00=w9[0],w01=w9[1],w02=w9[2],w10=w9[3],w11=w9[4],w12=w9[5],w20=w9[6],w21=w9[7],w22=w9[8];
    const float* xr = xs[d];
    union { unsigned short u[8]; int4 i4; } vals;
    #pragma unroll
    for (int j=0;j<8;j++){
        int key = (f&1)*32 + (j>>2)*16 + 4*lg + (j&3);
        int n = kt*64 + key;
        int hh = n/40, ww = n - hh*40;
        int col = key + 48;
        float acc = 0.f;
        if (hh > 0){
            if (ww > 0)  acc += xr[col-41]*w00;
                         acc += xr[col-40]*w01;
            if (ww < 39) acc += xr[col-39]*w02;
        }
        if (ww > 0)  acc += xr[col-1]*w10;
                     acc += xr[col]*w11;
        if (ww < 39) acc += xr[col+1]*w12;
        if (hh < 39){
            if (ww > 0)  acc += xr[col+39]*w20;
                         acc += xr[col+40]*w21;
            if (ww < 39) acc += xr[col+41]*w22;
        }
        float out = xr[col] + acc*inv + bias;
        vals.u[j] = f2bf(out);
    }
    *reinterpret_cast<int4*>(v_mf + ((size_t)(bi*4 + f)*64 + lane)*8) = vals.i4;
}

// ---------------- K3: qkv = SiLU(BN(W @ X)) -> qk_t[b][grp][n][d]; q channels pre-scaled ----------------
__global__ __launch_bounds__(256) void k_qkv(const unsigned short* __restrict__ x_t,
                                             const float* __restrict__ wq,
                                             const float* __restrict__ g,
                                             const float* __restrict__ be,
                                             const float* __restrict__ mu,
                                             const float* __restrict__ va,
                                             unsigned short* __restrict__ qk_t){
    __shared__ alignas(16) unsigned short a_lds[64*32];
    __shared__ alignas(16) unsigned short b_lds[64*32];
    int bi = blockIdx.x;                      // 4*8*25
    int b = bi / 200, ot = (bi/25) % 8, nt = bi % 25;
    int o0 = ot*64, n0 = nt*64;
    int tid = threadIdx.x, w = tid>>6, lane = tid&63;
    int row = tid>>2, col8 = (tid&3)*8;
    f32x4 acc[4];
    #pragma unroll
    for (int t=0;t<4;t++) acc[t] = (f32x4){0.f,0.f,0.f,0.f};
    const float* asrc = wq + (size_t)(o0+row)*256 + col8;
    const unsigned short* bsrc = x_t + ((size_t)b*N_SPATIAL + n0 + row)*256 + col8;
    for (int k0=0; k0<256; k0+=32){
        float4 f0 = *reinterpret_cast<const float4*>(asrc + k0);
        float4 f1 = *reinterpret_cast<const float4*>(asrc + k0 + 4);
        int4 av; av.x = pack2(f0.x,f0.y); av.y = pack2(f0.z,f0.w);
                 av.z = pack2(f1.x,f1.y); av.w = pack2(f1.z,f1.w);
        *reinterpret_cast<int4*>(&a_lds[row*32 + col8]) = av;
        *reinterpret_cast<int4*>(&b_lds[row*32 + col8]) = *reinterpret_cast<const int4*>(bsrc + k0);
        __syncthreads();
        short8 af = *reinterpret_cast<const short8*>(&a_lds[(16*w + (lane&15))*32 + (lane>>4)*8]);
        #pragma unroll
        for (int t=0;t<4;t++){
            short8 bf = *reinterpret_cast<const short8*>(&b_lds[(16*t + (lane&15))*32 + (lane>>4)*8]);
            acc[t] = __builtin_amdgcn_mfma_f32_16x16x32_bf16(af, bf, acc[t], 0, 0, 0);
        }
        __syncthreads();
    }
    #pragma unroll
    for (int r=0;r<4;r++){
        int o = o0 + 16*w + (lane>>4)*4 + r;
        float inv = g[o] * rsqrtf(va[o] + 1e-5f);
        float b2  = be[o] - mu[o]*inv;
        float qs  = (o < 256) ? QSCALE_LOG2E : 1.0f;
        int grp = o >> 5, d = o & 31;
        unsigned short* dst = qk_t + ((size_t)(b*16 + grp)*N_SPATIAL)*32 + d;
        #pragma unroll
        for (int t=0;t<4;t++){
            int n = n0 + 16*t + (lane&15);
            float z = acc[t][r]*inv + b2;
            float y = z / (1.f + __expf(-z));
            dst[(size_t)n*32] = f2bf(y * qs);
        }
    }
}

// ---------------- K4 v7: attention, producer/consumer waves, raw barriers, triple-buffered LDS ----------------
// 512 thr: waves 0-3 consume (16q each, no global loads in loop); waves 4-7 stage K/V tile kt+2.
__global__ __launch_bounds__(512) void k_attn7(const unsigned short* __restrict__ qk_t,
                                               const unsigned short* __restrict__ v_mf,
                                               unsigned short* __restrict__ ao_t){
    __shared__ alignas(16) unsigned short k_lds[3][64*40];   // padded stride 40 u16
    __shared__ alignas(16) unsigned short v_lds[3][2048];
    int bi = blockIdx.x;            // 800 = b*200 + h*25 + qt
    int b = bi/200, h = (bi/25)%8, qt = bi%25;
    int tid = threadIdx.x, w = tid>>6, lane = tid&63;

    const unsigned short* ksrc = qk_t + ((size_t)(b*16+8+h)*N_SPATIAL)*32;
    const unsigned short* vms  = v_mf + (size_t)(b*200 + h*25)*2048;

    if (w < 4){
        // ---------------- consumer ----------------
        int ql = lane&15, lg = lane>>4;
        int nq = qt*64 + w*16 + ql;
        const unsigned short* qsrc = qk_t + ((size_t)(b*16+h)*N_SPATIAL)*32;
        short8 qf = *reinterpret_cast<const short8*>(qsrc + (size_t)nq*32 + lg*8);
        f32x4 o0 = (f32x4){0.f,0.f,0.f,0.f};
        f32x4 o1 = (f32x4){0.f,0.f,0.f,0.f};
        float Sp = 0.f;

        asm volatile("" ::: "memory");
        __builtin_amdgcn_s_barrier();            // prologue barrier
        asm volatile("" ::: "memory");

        int cur = 0;
        for (int kt = 0; kt < 25; ++kt){
            const unsigned short* kb = &k_lds[cur][0];
            const unsigned short* vb = &v_lds[cur][0];
            short8 ka0 = *reinterpret_cast<const short8*>(kb + (size_t)( 0 + ql)*40 + lg*8);
            short8 ka1 = *reinterpret_cast<const short8*>(kb + (size_t)(16 + ql)*40 + lg*8);
            short8 ka2 = *reinterpret_cast<const short8*>(kb + (size_t)(32 + ql)*40 + lg*8);
            short8 ka3 = *reinterpret_cast<const short8*>(kb + (size_t)(48 + ql)*40 + lg*8);

            f32x4 z = (f32x4){0.f,0.f,0.f,0.f};
            f32x4 p0 = __builtin_amdgcn_mfma_f32_16x16x32_bf16(ka0, qf, z, 0,0,0);
            f32x4 p1 = __builtin_amdgcn_mfma_f32_16x16x32_bf16(ka1, qf, z, 0,0,0);
            f32x4 p2 = __builtin_amdgcn_mfma_f32_16x16x32_bf16(ka2, qf, z, 0,0,0);
            f32x4 p3 = __builtin_amdgcn_mfma_f32_16x16x32_bf16(ka3, qf, z, 0,0,0);

            #pragma unroll
            for (int r=0;r<4;r++){
                p0[r] = fexp2(p0[r]);
                p1[r] = fexp2(p1[r]);
                p2[r] = fexp2(p2[r]);
                p3[r] = fexp2(p3[r]);
            }
            Sp += ((p0[0]+p0[1])+(p0[2]+p0[3])) + ((p1[0]+p1[1])+(p1[2]+p1[3]))
                + ((p2[0]+p2[1])+(p2[2]+p2[3])) + ((p3[0]+p3[1])+(p3[2]+p3[3]));

            union { int4 i; short8 s8; } pb0, pb1;
            pb0.i = make_int4((int)cvtpk(p0[0],p0[1]), (int)cvtpk(p0[2],p0[3]),
                              (int)cvtpk(p1[0],p1[1]), (int)cvtpk(p1[2],p1[3]));
            pb1.i = make_int4((int)cvtpk(p2[0],p2[1]), (int)cvtpk(p2[2],p2[3]),
                              (int)cvtpk(p3[0],p3[1]), (int)cvtpk(p3[2],p3[3]));

            short8 va0 = *reinterpret_cast<const short8*>(vb +    0 + lane*8);
            short8 va1 = *reinterpret_cast<const short8*>(vb +  512 + lane*8);
            short8 va2 = *reinterpret_cast<const short8*>(vb + 1024 + lane*8);
            short8 va3 = *reinterpret_cast<const short8*>(vb + 1536 + lane*8);

            o0 = __builtin_amdgcn_mfma_f32_16x16x32_bf16(va0, pb0.s8, o0, 0,0,0);
            o0 = __builtin_amdgcn_mfma_f32_16x16x32_bf16(va1, pb1.s8, o0, 0,0,0);
            o1 = __builtin_amdgcn_mfma_f32_16x16x32_bf16(va2, pb0.s8, o1, 0,0,0);
            o1 = __builtin_amdgcn_mfma_f32_16x16x32_bf16(va3, pb1.s8, o1, 0,0,0);

            asm volatile("" ::: "memory");
            __builtin_amdgcn_s_barrier();
            asm volatile("" ::: "memory");
            cur = (cur==2) ? 0 : cur+1;
        }

        Sp += __shfl_xor(Sp, 16);
        Sp += __shfl_xor(Sp, 32);
        float inv = 1.f / Sp;
        size_t rowoff = ((size_t)b*N_SPATIAL + nq)*256 + h*32;
        uint2 w0 = make_uint2((unsigned)pack2(o0[0]*inv, o0[1]*inv),
                              (unsigned)pack2(o0[2]*inv, o0[3]*inv));
        *reinterpret_cast<uint2*>(ao_t + rowoff + 4*lg) = w0;
        uint2 w1 = make_uint2((unsigned)pack2(o1[0]*inv, o1[1]*inv),
                              (unsigned)pack2(o1[2]*inv, o1[3]*inv));
        *reinterpret_cast<uint2*>(ao_t + rowoff + 16 + 4*lg) = w1;
    } else {
        // ---------------- producer ----------------
        int pi = tid & 255;                         // 0..255
        const unsigned short* kg = ksrc + pi*8;
        const unsigned short* vg = vms  + pi*8;
        unsigned short* kd = &k_lds[0][0] + (pi>>2)*40 + (pi&3)*8;
        unsigned short* vd = &v_lds[0][0] + pi*8;

        // prologue: t0 -> buf0, t1 -> buf1, t2 held in regs
        int4 a0 = *reinterpret_cast<const int4*>(kg);
        int4 b0 = *reinterpret_cast<const int4*>(vg);
        *reinterpret_cast<int4*>(kd) = a0;
        *reinterpret_cast<int4*>(vd) = b0;
        int4 a1 = *reinterpret_cast<const int4*>(kg + 2048);
        int4 b1 = *reinterpret_cast<const int4*>(vg + 2048);
        *reinterpret_cast<int4*>(kd + 2560) = a1;
        *reinterpret_cast<int4*>(vd + 2048) = b1;
        int4 hk = *reinterpret_cast<const int4*>(kg + 4096);
        int4 hv = *reinterpret_cast<const int4*>(vg + 4096);
        asm volatile("s_waitcnt lgkmcnt(0)" ::: "memory");
        __builtin_amdgcn_s_barrier();               // prologue barrier
        asm volatile("" ::: "memory");

        int wb = 2;
        for (int kt = 0; kt < 25; ++kt){
            if (kt < 23){
                // write held tile kt+2 (compiler inserts counted vmcnt for hk/hv — 1 iter old)
                *reinterpret_cast<int4*>(kd + wb*2560) = hk;
                *reinterpret_cast<int4*>(vd + wb*2048) = hv;
            }
            if (kt < 22){
                hk = *reinterpret_cast<const int4*>(kg + (size_t)(kt+3)*2048);
                hv = *reinterpret_cast<const int4*>(vg + (size_t)(kt+3)*2048);
            }
            asm volatile("s_waitcnt lgkmcnt(0)" ::: "memory");
            __builtin_amdgcn_s_barrier();
            asm volatile("" ::: "memory");
            wb = (wb==2) ? 0 : wb+1;
        }
    }
}

// ---------------- K5: out = SiLU(BN(proj_w @ AO)) -> FLOAT32 out ----------------
__global__ __launch_bounds__(256) void k_proj(const unsigned short* __restrict__ ao_t,
                                              const float* __restrict__ wp,
                                              const float* __restrict__ g,
                                              const float* __restrict__ be,
                                              const float* __restrict__ mu,
                                              const float* __restrict__ va,
                                              float* __restrict__ out){
    __shared__ alignas(16) unsigned short a_lds[64*32];
    __shared__ alignas(16) unsigned short b_lds[64*32];
    int bi = blockIdx.x;                      // 4*4*25
    int b = bi / 100, ot = (bi/25) % 4, nt = bi % 25;
    int o0 = ot*64, n0 = nt*64;
    int tid = threadIdx.x, w = tid>>6, lane = tid&63;
    int row = tid>>2, col8 = (tid&3)*8;
    f32x4 acc[4];
    #pragma unroll
    for (int t=0;t<4;t++) acc[t] = (f32x4){0.f,0.f,0.f,0.f};
    const float* asrc = wp + (size_t)(o0+row)*256 + col8;
    const unsigned short* bsrc = ao_t + ((size_t)b*N_SPATIAL + n0 + row)*256 + col8;
    for (int k0=0; k0<256; k0+=32){
        float4 f0 = *reinterpret_cast<const float4*>(asrc + k0);
        float4 f1 = *reinterpret_cast<const float4*>(asrc + k0 + 4);
        int4 av; av.x = pack2(f0.x,f0.y); av.y = pack2(f0.z,f0.w);
                 av.z = pack2(f1.x,f1.y); av.w = pack2(f1.z,f1.w);
        *reinterpret_cast<int4*>(&a_lds[row*32 + col8]) = av;
        *reinterpret_cast<int4*>(&b_lds[row*32 + col8]) = *reinterpret_cast<const int4*>(bsrc + k0);
        __syncthreads();
        short8 af = *reinterpret_cast<const short8*>(&a_lds[(16*w + (lane&15))*32 + (lane>>4)*8]);
        #pragma unroll
        for (int t=0;t<4;t++){
            short8 bf = *reinterpret_cast<const short8*>(&b_lds[(16*t + (lane&15))*32 + (lane>>4)*8]);
            acc[t] = __builtin_amdgcn_mfma_f32_16x16x32_bf16(af, bf, acc[t], 0, 0, 0);
        }
        __syncthreads();
    }
    #pragma unroll
    for (int r=0;r<4;r++){
        int o = o0 + 16*w + (lane>>4)*4 + r;
        float inv = g[o] * rsqrtf(va[o] + 1e-5f);
        float b2  = be[o] - mu[o]*inv;
        float* dst = out + ((size_t)(b*256 + o))*N_SPATIAL;
        #pragma unroll
        for (int t=0;t<4;t++){
            int n = n0 + 16*t + (lane&15);
            float z = acc[t][r]*inv + b2;
            float y = z / (1.f + __expf(-z));
            dst[n] = y;
        }
    }
}

extern "C" void kernel_launch(void* const* d_in, const int* in_sizes, int n_in,
                              void* d_out, int out_size, void* d_ws, size_t ws_size,
                              hipStream_t stream) {
    const float* x      = (const float*)d_in[0];
    const float* qkv_w  = (const float*)d_in[1];
    const float* qkv_g  = (const float*)d_in[2];
    const float* qkv_b  = (const float*)d_in[3];
    const float* qkv_m  = (const float*)d_in[4];
    const float* qkv_v  = (const float*)d_in[5];
    const float* proj_w = (const float*)d_in[6];
    const float* proj_g = (const float*)d_in[7];
    const float* proj_b = (const float*)d_in[8];
    const float* proj_m = (const float*)d_in[9];
    const float* proj_v = (const float*)d_in[10];
    const float* pe_w   = (const float*)d_in[11];
    const float* pe_g   = (const float*)d_in[12];
    const float* pe_b   = (const float*)d_in[13];
    const float* pe_m   = (const float*)d_in[14];
    const float* pe_v   = (const float*)d_in[15];

    char* ws = (char*)d_ws;
    unsigned short* x_t  = (unsigned short*)(ws);                 // 3,276,800
    unsigned short* v_mf = (unsigned short*)(ws + 3276800);       // 3,276,800
    unsigned short* qk_t = (unsigned short*)(ws + 6553600);       // 6,553,600
    unsigned short* ao_t = (unsigned short*)(ws + 13107200);      // 3,276,800
    float* outp = (float*)d_out;

    k_xt   <<<200, 256, 0, stream>>>(x, x_t);
    k_pev3 <<<800, 256, 0, stream>>>(x, pe_w, pe_g, pe_b, pe_m, pe_v, v_mf);
    k_qkv  <<<800, 256, 0, stream>>>(x_t, qkv_w, qkv_g, qkv_b, qkv_m, qkv_v, qk_t);
    k_attn7<<<800, 512, 0, stream>>>(qk_t, v_mf, ao_t);
    k_proj <<<400, 256, 0, stream>>>(ao_t, proj_w, proj_g, proj_b, proj_m, proj_v, outp);
}

// Round 13
// 59.216 us; speedup vs baseline: 2.3509x; 1.1624x over previous
//
#include <hip/hip_runtime.h>
#include <hip/hip_bf16.h>

typedef __attribute__((ext_vector_type(8))) short short8;
typedef __attribute__((ext_vector_type(4))) float f32x4;

__device__ __forceinline__ unsigned short f2bf(float f){
    union { float f; unsigned u; } uf; uf.f = f;
    unsigned u = uf.u;
    u += 0x7FFFu + ((u >> 16) & 1u);   // RNE
    return (unsigned short)(u >> 16);
}
__device__ __forceinline__ int pack2(float a, float b){
    union { float f; unsigned u; } ua, ub; ua.f = a; ub.f = b;
    unsigned x = ua.u; x += 0x7FFFu + ((x >> 16) & 1u);
    unsigned y = ub.u; y += 0x7FFFu + ((y >> 16) & 1u);
    return (int)((x >> 16) | (y & 0xFFFF0000u));
}
__device__ __forceinline__ unsigned cvtpk(float lo, float hi){
    unsigned r;
    asm("v_cvt_pk_bf16_f32 %0, %1, %2" : "=v"(r) : "v"(lo), "v"(hi));
    return r;
}
__device__ __forceinline__ float fexp2(float x){
    return __builtin_amdgcn_exp2f(x);   // v_exp_f32: 2^x
}

#define N_SPATIAL 1600
#define QSCALE_LOG2E 0.25506601f   /* 32^-0.5 * log2(e), folded into q */
#define LSTR 40                    /* padded LDS row stride (u16) for GEMM tiles */

// ---------------- K1 fused: [0,200) x->x_t transpose ; [200,1000) pev (V in MFMA frag order) ----------------
__global__ __launch_bounds__(256) void k_head(const float* __restrict__ x,
                                              const float* __restrict__ pw,
                                              const float* __restrict__ pg,
                                              const float* __restrict__ pb,
                                              const float* __restrict__ pm,
                                              const float* __restrict__ pv,
                                              unsigned short* __restrict__ x_t,
                                              unsigned short* __restrict__ v_mf){
    __shared__ float xs[32][163];
    int bi = blockIdx.x;
    int t = threadIdx.x;
    if (bi < 200){
        // ---- transpose: x f32 (B,C,N) -> x_t bf16 (B,N,C) ----
        int b = bi / 50, nc = bi % 50;
        int n0 = nc * 32;
        int c = t;
        unsigned short vals[32];
        const float* src = x + ((size_t)(b*256 + c))*N_SPATIAL + n0;
        #pragma unroll
        for (int j=0;j<8;j++){
            float4 f = *reinterpret_cast<const float4*>(src + j*4);
            vals[j*4+0] = f2bf(f.x); vals[j*4+1] = f2bf(f.y);
            vals[j*4+2] = f2bf(f.z); vals[j*4+3] = f2bf(f.w);
        }
        unsigned short* dst = x_t + ((size_t)b*N_SPATIAL + n0)*256 + c;
        #pragma unroll
        for (int j=0;j<32;j++) dst[(size_t)j*256] = vals[j];
        return;
    }
    // ---- pev: v = x + BN(dwconv3x3(x)) -> v_mf frag order, LDS-staged window ----
    int pbi = bi - 200;               // 800 = b*200 + h*25 + kt
    int b = pbi/200, h=(pbi/25)%8, kt=pbi%25;
    int winStart = kt*64 - 48;
    const float* xbase = x + ((size_t)(b*256 + h*32))*N_SPATIAL;
    #pragma unroll
    for (int i=0;i<20;i++){
        int idx = t + i*256;          // < 5120 = 32*160
        int row = idx / 160, col = idx - row*160;
        int n = winStart + col;
        float val = ((unsigned)n < 1600u) ? xbase[(size_t)row*N_SPATIAL + n] : 0.f;
        xs[row][col] = val;
    }
    __syncthreads();

    int f = t>>6, lane = t&63, ql = lane&15, lg = lane>>4;
    int d = (f>>1)*16 + ql;
    int c = h*32 + d;
    float inv = pg[c]*rsqrtf(pv[c]+1e-5f);
    float bias = pb[c]-pm[c]*inv;
    const float* w9 = pw + c*9;
    float w00=w9[0],w01=w9[1],w02=w9[2],w10=w9[3],w11=w9[4],w12=w9[5],w20=w9[6],w21=w9[7],w22=w9[8];
    const float* xr = xs[d];
    union { unsigned short u[8]; int4 i4; } vals;
    #pragma unroll
    for (int j=0;j<8;j++){
        int key = (f&1)*32 + (j>>2)*16 + 4*lg + (j&3);
        int n = kt*64 + key;
        int hh = n/40, ww = n - hh*40;
        int col = key + 48;
        float acc = 0.f;
        if (hh > 0){
            if (ww > 0)  acc += xr[col-41]*w00;
                         acc += xr[col-40]*w01;
            if (ww < 39) acc += xr[col-39]*w02;
        }
        if (ww > 0)  acc += xr[col-1]*w10;
                     acc += xr[col]*w11;
        if (ww < 39) acc += xr[col+1]*w12;
        if (hh < 39){
            if (ww > 0)  acc += xr[col+39]*w20;
                         acc += xr[col+40]*w21;
            if (ww < 39) acc += xr[col+41]*w22;
        }
        float out = xr[col] + acc*inv + bias;
        vals.u[j] = f2bf(out);
    }
    *reinterpret_cast<int4*>(v_mf + ((size_t)(pbi*4 + f)*64 + lane)*8) = vals.i4;
}

// ---------------- K2: qkv GEMM, padded LDS (no bank conflicts), packed 8B stores ----------------
__global__ __launch_bounds__(256) void k_qkv2(const unsigned short* __restrict__ x_t,
                                              const float* __restrict__ wq,
                                              const float* __restrict__ g,
                                              const float* __restrict__ be,
                                              const float* __restrict__ mu,
                                              const float* __restrict__ va,
                                              unsigned short* __restrict__ qk_t){
    __shared__ alignas(16) unsigned short a_lds[64*LSTR];
    __shared__ alignas(16) unsigned short b_lds[64*LSTR];
    int bi = blockIdx.x;                      // 4*8*25
    int b = bi / 200, ot = (bi/25) % 8, nt = bi % 25;
    int o0 = ot*64, n0 = nt*64;
    int tid = threadIdx.x, w = tid>>6, lane = tid&63;
    int row = tid>>2, col8 = (tid&3)*8;
    int ql = lane&15, lg = lane>>4;
    f32x4 acc[4];
    #pragma unroll
    for (int t=0;t<4;t++) acc[t] = (f32x4){0.f,0.f,0.f,0.f};
    const float* asrc = wq + (size_t)(o0+row)*256 + col8;
    const unsigned short* bsrc = x_t + ((size_t)b*N_SPATIAL + n0 + row)*256 + col8;
    for (int k0=0; k0<256; k0+=32){
        float4 f0 = *reinterpret_cast<const float4*>(asrc + k0);
        float4 f1 = *reinterpret_cast<const float4*>(asrc + k0 + 4);
        int4 av; av.x = pack2(f0.x,f0.y); av.y = pack2(f0.z,f0.w);
                 av.z = pack2(f1.x,f1.y); av.w = pack2(f1.z,f1.w);
        *reinterpret_cast<int4*>(&a_lds[row*LSTR + col8]) = av;
        *reinterpret_cast<int4*>(&b_lds[row*LSTR + col8]) = *reinterpret_cast<const int4*>(bsrc + k0);
        __syncthreads();
        short8 af = *reinterpret_cast<const short8*>(&a_lds[(16*w + ql)*LSTR + lg*8]);
        #pragma unroll
        for (int t=0;t<4;t++){
            short8 bf = *reinterpret_cast<const short8*>(&b_lds[(16*t + ql)*LSTR + lg*8]);
            acc[t] = __builtin_amdgcn_mfma_f32_16x16x32_bf16(af, bf, acc[t], 0, 0, 0);
        }
        __syncthreads();
    }
    // o = o0 + 16w + 4lg + r, r=0..3 consecutive -> one 8B store per t
    int ob = o0 + 16*w + 4*lg;
    int grp = ob >> 5, d0 = ob & 31;
    float invr[4], b2r[4];
    #pragma unroll
    for (int r=0;r<4;r++){
        int o = ob + r;
        invr[r] = g[o] * rsqrtf(va[o] + 1e-5f);
        b2r[r]  = be[o] - mu[o]*invr[r];
    }
    float qs = (ob < 256) ? QSCALE_LOG2E : 1.0f;
    unsigned short* dstb = qk_t + ((size_t)(b*16 + grp)*N_SPATIAL)*32 + d0;
    #pragma unroll
    for (int t=0;t<4;t++){
        int n = n0 + 16*t + ql;
        float y[4];
        #pragma unroll
        for (int r=0;r<4;r++){
            float z = acc[t][r]*invr[r] + b2r[r];
            y[r] = (z / (1.f + __expf(-z))) * qs;
        }
        uint2 wv = make_uint2((unsigned)pack2(y[0],y[1]), (unsigned)pack2(y[2],y[3]));
        *reinterpret_cast<uint2*>(dstb + (size_t)n*32) = wv;
    }
}

// ---------------- K3: attention v7 + XCD swizzle ----------------
__global__ __launch_bounds__(512) void k_attn7(const unsigned short* __restrict__ qk_t,
                                               const unsigned short* __restrict__ v_mf,
                                               unsigned short* __restrict__ ao_t){
    __shared__ alignas(16) unsigned short k_lds[3][64*40];
    __shared__ alignas(16) unsigned short v_lds[3][2048];
    // XCD-swizzle: group the 25 qt-blocks of one (b,h) onto one XCD's L2
    int l = blockIdx.x;
    int xc = l & 7, j = l >> 3;
    int gg = xc + 8*(j/25);
    int bi = 25*gg + (j%25);
    int b = gg >> 3, h = gg & 7, qt = bi % 25;
    int tid = threadIdx.x, w = tid>>6, lane = tid&63;

    const unsigned short* ksrc = qk_t + ((size_t)(b*16+8+h)*N_SPATIAL)*32;
    const unsigned short* vms  = v_mf + (size_t)(b*200 + h*25)*2048;

    if (w < 4){
        // consumer
        int ql = lane&15, lg = lane>>4;
        int nq = qt*64 + w*16 + ql;
        const unsigned short* qsrc = qk_t + ((size_t)(b*16+h)*N_SPATIAL)*32;
        short8 qf = *reinterpret_cast<const short8*>(qsrc + (size_t)nq*32 + lg*8);
        f32x4 o0 = (f32x4){0.f,0.f,0.f,0.f};
        f32x4 o1 = (f32x4){0.f,0.f,0.f,0.f};
        float Sp = 0.f;

        asm volatile("" ::: "memory");
        __builtin_amdgcn_s_barrier();
        asm volatile("" ::: "memory");

        int cur = 0;
        for (int kt = 0; kt < 25; ++kt){
            const unsigned short* kb = &k_lds[cur][0];
            const unsigned short* vb = &v_lds[cur][0];
            short8 ka0 = *reinterpret_cast<const short8*>(kb + (size_t)( 0 + ql)*40 + lg*8);
            short8 ka1 = *reinterpret_cast<const short8*>(kb + (size_t)(16 + ql)*40 + lg*8);
            short8 ka2 = *reinterpret_cast<const short8*>(kb + (size_t)(32 + ql)*40 + lg*8);
            short8 ka3 = *reinterpret_cast<const short8*>(kb + (size_t)(48 + ql)*40 + lg*8);

            f32x4 z = (f32x4){0.f,0.f,0.f,0.f};
            f32x4 p0 = __builtin_amdgcn_mfma_f32_16x16x32_bf16(ka0, qf, z, 0,0,0);
            f32x4 p1 = __builtin_amdgcn_mfma_f32_16x16x32_bf16(ka1, qf, z, 0,0,0);
            f32x4 p2 = __builtin_amdgcn_mfma_f32_16x16x32_bf16(ka2, qf, z, 0,0,0);
            f32x4 p3 = __builtin_amdgcn_mfma_f32_16x16x32_bf16(ka3, qf, z, 0,0,0);

            #pragma unroll
            for (int r=0;r<4;r++){
                p0[r] = fexp2(p0[r]);
                p1[r] = fexp2(p1[r]);
                p2[r] = fexp2(p2[r]);
                p3[r] = fexp2(p3[r]);
            }
            Sp += ((p0[0]+p0[1])+(p0[2]+p0[3])) + ((p1[0]+p1[1])+(p1[2]+p1[3]))
                + ((p2[0]+p2[1])+(p2[2]+p2[3])) + ((p3[0]+p3[1])+(p3[2]+p3[3]));

            union { int4 i; short8 s8; } pb0, pb1;
            pb0.i = make_int4((int)cvtpk(p0[0],p0[1]), (int)cvtpk(p0[2],p0[3]),
                              (int)cvtpk(p1[0],p1[1]), (int)cvtpk(p1[2],p1[3]));
            pb1.i = make_int4((int)cvtpk(p2[0],p2[1]), (int)cvtpk(p2[2],p2[3]),
                              (int)cvtpk(p3[0],p3[1]), (int)cvtpk(p3[2],p3[3]));

            short8 va0 = *reinterpret_cast<const short8*>(vb +    0 + lane*8);
            short8 va1 = *reinterpret_cast<const short8*>(vb +  512 + lane*8);
            short8 va2 = *reinterpret_cast<const short8*>(vb + 1024 + lane*8);
            short8 va3 = *reinterpret_cast<const short8*>(vb + 1536 + lane*8);

            o0 = __builtin_amdgcn_mfma_f32_16x16x32_bf16(va0, pb0.s8, o0, 0,0,0);
            o0 = __builtin_amdgcn_mfma_f32_16x16x32_bf16(va1, pb1.s8, o0, 0,0,0);
            o1 = __builtin_amdgcn_mfma_f32_16x16x32_bf16(va2, pb0.s8, o1, 0,0,0);
            o1 = __builtin_amdgcn_mfma_f32_16x16x32_bf16(va3, pb1.s8, o1, 0,0,0);

            asm volatile("" ::: "memory");
            __builtin_amdgcn_s_barrier();
            asm volatile("" ::: "memory");
            cur = (cur==2) ? 0 : cur+1;
        }

        Sp += __shfl_xor(Sp, 16);
        Sp += __shfl_xor(Sp, 32);
        float inv = 1.f / Sp;
        size_t rowoff = ((size_t)b*N_SPATIAL + nq)*256 + h*32;
        uint2 w0 = make_uint2((unsigned)pack2(o0[0]*inv, o0[1]*inv),
                              (unsigned)pack2(o0[2]*inv, o0[3]*inv));
        *reinterpret_cast<uint2*>(ao_t + rowoff + 4*lg) = w0;
        uint2 w1 = make_uint2((unsigned)pack2(o1[0]*inv, o1[1]*inv),
                              (unsigned)pack2(o1[2]*inv, o1[3]*inv));
        *reinterpret_cast<uint2*>(ao_t + rowoff + 16 + 4*lg) = w1;
    } else {
        // producer
        int pi = tid & 255;
        const unsigned short* kg = ksrc + pi*8;
        const unsigned short* vg = vms  + pi*8;
        unsigned short* kd = &k_lds[0][0] + (pi>>2)*40 + (pi&3)*8;
        unsigned short* vd = &v_lds[0][0] + pi*8;

        int4 a0 = *reinterpret_cast<const int4*>(kg);
        int4 b0 = *reinterpret_cast<const int4*>(vg);
        *reinterpret_cast<int4*>(kd) = a0;
        *reinterpret_cast<int4*>(vd) = b0;
        int4 a1 = *reinterpret_cast<const int4*>(kg + 2048);
        int4 b1 = *reinterpret_cast<const int4*>(vg + 2048);
        *reinterpret_cast<int4*>(kd + 2560) = a1;
        *reinterpret_cast<int4*>(vd + 2048) = b1;
        int4 hk = *reinterpret_cast<const int4*>(kg + 4096);
        int4 hv = *reinterpret_cast<const int4*>(vg + 4096);
        asm volatile("s_waitcnt lgkmcnt(0)" ::: "memory");
        __builtin_amdgcn_s_barrier();
        asm volatile("" ::: "memory");

        int wb = 2;
        for (int kt = 0; kt < 25; ++kt){
            if (kt < 23){
                *reinterpret_cast<int4*>(kd + wb*2560) = hk;
                *reinterpret_cast<int4*>(vd + wb*2048) = hv;
            }
            if (kt < 22){
                hk = *reinterpret_cast<const int4*>(kg + (size_t)(kt+3)*2048);
                hv = *reinterpret_cast<const int4*>(vg + (size_t)(kt+3)*2048);
            }
            asm volatile("s_waitcnt lgkmcnt(0)" ::: "memory");
            __builtin_amdgcn_s_barrier();
            asm volatile("" ::: "memory");
            wb = (wb==2) ? 0 : wb+1;
        }
    }
}

// ---------------- K4: proj GEMM, padded LDS ----------------
__global__ __launch_bounds__(256) void k_proj2(const unsigned short* __restrict__ ao_t,
                                               const float* __restrict__ wp,
                                               const float* __restrict__ g,
                                               const float* __restrict__ be,
                                               const float* __restrict__ mu,
                                               const float* __restrict__ va,
                                               float* __restrict__ out){
    __shared__ alignas(16) unsigned short a_lds[64*LSTR];
    __shared__ alignas(16) unsigned short b_lds[64*LSTR];
    int bi = blockIdx.x;                      // 4*4*25
    int b = bi / 100, ot = (bi/25) % 4, nt = bi % 25;
    int o0 = ot*64, n0 = nt*64;
    int tid = threadIdx.x, w = tid>>6, lane = tid&63;
    int row = tid>>2, col8 = (tid&3)*8;
    int ql = lane&15, lg = lane>>4;
    f32x4 acc[4];
    #pragma unroll
    for (int t=0;t<4;t++) acc[t] = (f32x4){0.f,0.f,0.f,0.f};
    const float* asrc = wp + (size_t)(o0+row)*256 + col8;
    const unsigned short* bsrc = ao_t + ((size_t)b*N_SPATIAL + n0 + row)*256 + col8;
    for (int k0=0; k0<256; k0+=32){
        float4 f0 = *reinterpret_cast<const float4*>(asrc + k0);
        float4 f1 = *reinterpret_cast<const float4*>(asrc + k0 + 4);
        int4 av; av.x = pack2(f0.x,f0.y); av.y = pack2(f0.z,f0.w);
                 av.z = pack2(f1.x,f1.y); av.w = pack2(f1.z,f1.w);
        *reinterpret_cast<int4*>(&a_lds[row*LSTR + col8]) = av;
        *reinterpret_cast<int4*>(&b_lds[row*LSTR + col8]) = *reinterpret_cast<const int4*>(bsrc + k0);
        __syncthreads();
        short8 af = *reinterpret_cast<const short8*>(&a_lds[(16*w + ql)*LSTR + lg*8]);
        #pragma unroll
        for (int t=0;t<4;t++){
            short8 bf = *reinterpret_cast<const short8*>(&b_lds[(16*t + ql)*LSTR + lg*8]);
            acc[t] = __builtin_amdgcn_mfma_f32_16x16x32_bf16(af, bf, acc[t], 0, 0, 0);
        }
        __syncthreads();
    }
    #pragma unroll
    for (int r=0;r<4;r++){
        int o = o0 + 16*w + lg*4 + r;
        float inv = g[o] * rsqrtf(va[o] + 1e-5f);
        float b2  = be[o] - mu[o]*inv;
        float* dst = out + ((size_t)(b*256 + o))*N_SPATIAL;
        #pragma unroll
        for (int t=0;t<4;t++){
            int n = n0 + 16*t + ql;
            float z = acc[t][r]*inv + b2;
            float y = z / (1.f + __expf(-z));
            dst[n] = y;
        }
    }
}

extern "C" void kernel_launch(void* const* d_in, const int* in_sizes, int n_in,
                              void* d_out, int out_size, void* d_ws, size_t ws_size,
                              hipStream_t stream) {
    const float* x      = (const float*)d_in[0];
    const float* qkv_w  = (const float*)d_in[1];
    const float* qkv_g  = (const float*)d_in[2];
    const float* qkv_b  = (const float*)d_in[3];
    const float* qkv_m  = (const float*)d_in[4];
    const float* qkv_v  = (const float*)d_in[5];
    const float* proj_w = (const float*)d_in[6];
    const float* proj_g = (const float*)d_in[7];
    const float* proj_b = (const float*)d_in[8];
    const float* proj_m = (const float*)d_in[9];
    const float* proj_v = (const float*)d_in[10];
    const float* pe_w   = (const float*)d_in[11];
    const float* pe_g   = (const float*)d_in[12];
    const float* pe_b   = (const float*)d_in[13];
    const float* pe_m   = (const float*)d_in[14];
    const float* pe_v   = (const float*)d_in[15];

    char* ws = (char*)d_ws;
    unsigned short* x_t  = (unsigned short*)(ws);                 // 3,276,800
    unsigned short* v_mf = (unsigned short*)(ws + 3276800);       // 3,276,800
    unsigned short* qk_t = (unsigned short*)(ws + 6553600);       // 6,553,600
    unsigned short* ao_t = (unsigned short*)(ws + 13107200);      // 3,276,800
    float* outp = (float*)d_out;

    k_head <<<1000,256, 0, stream>>>(x, pe_w, pe_g, pe_b, pe_m, pe_v, x_t, v_mf);
    k_qkv2 <<<800, 256, 0, stream>>>(x_t, qkv_w, qkv_g, qkv_b, qkv_m, qkv_v, qk_t);
    k_attn7<<<800, 512, 0, stream>>>(qk_t, v_mf, ao_t);
    k_proj2<<<400, 256, 0, stream>>>(ao_t, proj_w, proj_g, proj_b, proj_m, proj_v, outp);
}